// Round 4
// baseline (468.649 us; speedup 1.0000x reference)
//
#include <hip/hip_runtime.h>
#include <hip/hip_bf16.h>
#include <hip/hip_fp16.h>

static constexpr int HN = 32;     // Hemb == Hgcn == 32
static constexpr int NIN = 128;
static constexpr int CH1 = 4096;  // edges per phase-1 block (40KB LDS -> 4 blk/CU)
static constexpr int CAP2 = 16384; // LDS stage capacity (ints) in phase 2b
static constexpr float LOG2E = 1.4426950408889634f;

__device__ __forceinline__ float bf2f(unsigned short u) {
    union { unsigned int i; float f; } v;
    v.i = ((unsigned int)u) << 16;
    return v.f;
}
__device__ __forceinline__ float ldf(const void* p, size_t i, int isbf) {
    return isbf ? bf2f(((const unsigned short*)p)[i]) : ((const float*)p)[i];
}
__device__ __forceinline__ unsigned int pack2h(float a, float b) {
    unsigned short ua = __half_as_ushort(__float2half_rn(a));
    unsigned short ub = __half_as_ushort(__float2half_rn(b));
    return (unsigned int)ua | ((unsigned int)ub << 16);
}
__device__ __forceinline__ float2 up2(unsigned int u) {
    __half2 h2;
    *reinterpret_cast<unsigned int*>(&h2) = u;
    return __half22float2(h2);
}

// K0: bf16-vs-fp32 input sniff (validated fp32; kept as insurance).
__global__ void detect_kernel(const unsigned int* __restrict__ xw,
                              int* __restrict__ flag)
{
    int lane = threadIdx.x;          // 64 threads
    int hits = 0;
    #pragma unroll
    for (int k = 0; k < 2; ++k) {
        unsigned int w = xw[lane + 64 * k];
        float a = bf2f((unsigned short)(w & 0xFFFFu));
        float aa = fabsf(a);
        if (a == 0.0f || (aa >= 0.000244140625f && aa <= 32.0f)) hits++;
    }
    #pragma unroll
    for (int m = 32; m; m >>= 1) hits += __shfl_xor(hits, m, 64);
    if (lane == 0) flag[0] = (hits >= 64) ? 1 : 0;
}

// K1: h = relu(x @ Wemb + bemb) -> fp32.
__global__ __launch_bounds__(256) void embed1_kernel(
    const void* __restrict__ x,
    const void* __restrict__ Wemb,
    const void* __restrict__ bemb,
    const int* __restrict__ flagp,
    float* __restrict__ h, int N)
{
    __shared__ float We[NIN * HN];
    __shared__ float be[HN];
    __shared__ float xs[32][NIN];
    const int tid = threadIdx.x;
    const int isbf = flagp[0];

    for (int i = tid; i < NIN * HN; i += 256) We[i] = ldf(Wemb, i, isbf);
    if (tid < HN) be[tid] = ldf(bemb, tid, isbf);

    const int n0 = blockIdx.x * 32;
    if (isbf) {
        const ushort4* x4 = (const ushort4*)((const unsigned short*)x + (size_t)n0 * NIN);
        for (int i = tid; i < 32 * (NIN / 4); i += 256) {
            ushort4 u = x4[i];
            int base = i * 4, n = base >> 7, k = base & (NIN - 1);
            xs[n][k] = bf2f(u.x); xs[n][k + 1] = bf2f(u.y);
            xs[n][k + 2] = bf2f(u.z); xs[n][k + 3] = bf2f(u.w);
        }
    } else {
        const float4* x4 = (const float4*)((const float*)x + (size_t)n0 * NIN);
        for (int i = tid; i < 32 * (NIN / 4); i += 256) {
            float4 u = x4[i];
            int base = i * 4, n = base >> 7, k = base & (NIN - 1);
            xs[n][k] = u.x; xs[n][k + 1] = u.y;
            xs[n][k + 2] = u.z; xs[n][k + 3] = u.w;
        }
    }
    __syncthreads();

    const int f = tid & 31, ns = tid >> 5;
    float a0 = be[f], a1 = be[f], a2 = be[f], a3 = be[f];
    #pragma unroll 8
    for (int k = 0; k < NIN; ++k) {
        float w = We[k * HN + f];
        a0 += xs[ns +  0][k] * w;
        a1 += xs[ns +  8][k] * w;
        a2 += xs[ns + 16][k] * w;
        a3 += xs[ns + 24][k] * w;
    }
    if (n0 + ns      < N) h[(size_t)(n0 + ns     ) * HN + f] = fmaxf(a0, 0.f);
    if (n0 + ns +  8 < N) h[(size_t)(n0 + ns +  8) * HN + f] = fmaxf(a1, 0.f);
    if (n0 + ns + 16 < N) h[(size_t)(n0 + ns + 16) * HN + f] = fmaxf(a2, 0.f);
    if (n0 + ns + 24 < N) h[(size_t)(n0 + ns + 24) * HN + f] = fmaxf(a3, 0.f);
}

// K2: per-node degree via direct device-scope atomics (count pre-zeroed).
// Replaces bhist + phase2a; bucket bases fall out of the rowptr scan.
__global__ __launch_bounds__(256) void degcnt_kernel(
    const int* __restrict__ col, int* __restrict__ count, int E)
{
    const int stride = gridDim.x * 256;
    for (int i = blockIdx.x * 256 + threadIdx.x; i < E; i += stride)
        atomicAdd(&count[col[i]], 1);
}

// K4 (phase1): bucketize edges with LDS reorder -> semi-coalesced writes of
// packed words (row<<8 | col&255) grouped by bucket. bucket = col>>8.
__global__ __launch_bounds__(512) void phase1_kernel(
    const int* __restrict__ row, const int* __restrict__ col,
    int* __restrict__ bucket_cursor, int* __restrict__ bucketed, int E, int B)
{
    __shared__ int hist[512];
    __shared__ int sc[512];
    __shared__ int cnt[512];
    __shared__ int gbase[512];
    __shared__ int word[CH1];
    __shared__ int dst[CH1];
    const int t = threadIdx.x;
    const int e0 = blockIdx.x * CH1;
    const int M = (E - e0 < CH1) ? (E - e0) : CH1;

    for (int i = t; i < B; i += 512) { hist[i] = 0; cnt[i] = 0; }
    __syncthreads();
    #pragma unroll
    for (int k = 0; k < CH1 / 512; ++k) {
        int e = e0 + k * 512 + t;
        if (e < E) atomicAdd(&hist[col[e] >> 8], 1);
    }
    __syncthreads();
    sc[t] = (t < B) ? hist[t] : 0;
    __syncthreads();
    for (int o = 1; o < 512; o <<= 1) {
        int v = (t >= o) ? sc[t - o] : 0;
        __syncthreads();
        sc[t] += v;
        __syncthreads();
    }
    if (t < B && hist[t])
        gbase[t] = atomicAdd(&bucket_cursor[t], hist[t]);
    __syncthreads();
    #pragma unroll
    for (int k = 0; k < CH1 / 512; ++k) {
        int e = e0 + k * 512 + t;
        if (e < E) {
            int c = col[e], r = row[e];
            int b = c >> 8;
            int lr = atomicAdd(&cnt[b], 1);
            int p = sc[b] - hist[b] + lr;     // exclusive scan + rank
            word[p] = (r << 8) | (c & 255);
            dst[p] = gbase[b] + lr;
        }
    }
    __syncthreads();
    for (int i = t; i < M; i += 512)
        bucketed[dst[i]] = word[i];
}

// K6a: per-2048-chunk sums (for rowptr scan)
__global__ __launch_bounds__(256) void scan1_kernel(
    const int* __restrict__ count, int* __restrict__ bsum, int N)
{
    __shared__ int s[256];
    const int t = threadIdx.x, b = blockIdx.x;
    int base = b * 2048 + t * 8, sum = 0;
    #pragma unroll
    for (int k = 0; k < 8; ++k) { int i = base + k; if (i < N) sum += count[i]; }
    s[t] = sum; __syncthreads();
    for (int o = 128; o; o >>= 1) { if (t < o) s[t] += s[t + o]; __syncthreads(); }
    if (t == 0) bsum[b] = s[0];
}

// K6b: wave-parallel exclusive scan of chunk sums (nsb <= 64); rowptr[N] = E
__global__ void scan2_kernel(int* __restrict__ bsum, int nsb,
                             int* __restrict__ rowptr, int N, int E)
{
    const int lane = threadIdx.x;   // 64 threads
    if (nsb <= 64) {
        int v = (lane < nsb) ? bsum[lane] : 0;
        int s = v;
        #pragma unroll
        for (int o = 1; o < 64; o <<= 1) {
            int u = __shfl_up(s, o, 64);
            if (lane >= o) s += u;
        }
        if (lane < nsb) bsum[lane] = s - v;
    } else if (lane == 0) {
        int acc = 0;
        for (int i = 0; i < nsb; ++i) { int v = bsum[i]; bsum[i] = acc; acc += v; }
    }
    if (lane == 0) rowptr[N] = E;
}

// K6c: rowptr = exclusive prefix of count; cursor (in-place) = rowptr;
// bucket_cursor[b] = rowptr[b<<8] (phase1 write bases).
__global__ __launch_bounds__(256) void scan3_kernel(
    int* __restrict__ countcur, const int* __restrict__ bsum,
    int* __restrict__ rowptr, int* __restrict__ bucket_cursor, int N)
{
    __shared__ int s[256];
    const int t = threadIdx.x, b = blockIdx.x;
    int base = b * 2048 + t * 8;
    int c[8]; int sum = 0;
    #pragma unroll
    for (int k = 0; k < 8; ++k) {
        int i = base + k;
        c[k] = (i < N) ? countcur[i] : 0;
        sum += c[k];
    }
    s[t] = sum; __syncthreads();
    for (int o = 1; o < 256; o <<= 1) {
        int v = (t >= o) ? s[t - o] : 0;
        __syncthreads();
        s[t] += v;
        __syncthreads();
    }
    int acc = bsum[b] + ((t == 0) ? 0 : s[t - 1]);
    #pragma unroll
    for (int k = 0; k < 8; ++k) {
        int i = base + k;
        if (i < N) {
            rowptr[i] = acc;
            countcur[i] = acc;
            if ((i & 255) == 0) bucket_cursor[i >> 8] = acc;
            acc += c[k];
        }
    }
}

// K7 (phase2b): fine CSR placement. One block per bucket; stage segment in
// LDS, copy out fully coalesced. Bucket bounds read from rowptr directly.
// NOTE: rps[0..nodes] INCLUSIVE must all be loaded (nodes can be 256, so
// the strided loop lets thread 0 also fetch rps[256] — round-2/3 crash fix).
__global__ __launch_bounds__(256) void phase2b_kernel(
    const int* __restrict__ bucketed,
    const int* __restrict__ rowptr, int* __restrict__ cursor,
    int* __restrict__ csr_src, int N)
{
    __shared__ int stage[CAP2];
    __shared__ int rps[257];
    __shared__ int cnt[256];
    const int t = threadIdx.x, b = blockIdx.x;
    const int node0 = b << 8;
    const int nodes = (N - node0 < 256) ? (N - node0) : 256;
    for (int i = t; i <= nodes; i += 256) rps[i] = rowptr[node0 + i];
    cnt[t] = 0;
    __syncthreads();
    const int s0 = rps[0], s1 = rps[nodes];
    const int segsz = s1 - s0;
    if (segsz <= CAP2) {
        for (int i = s0 + t; i < s1; i += 256) {
            int w = bucketed[i];
            int lc = w & 255;
            int off = rps[lc] - s0 + atomicAdd(&cnt[lc], 1);
            stage[off] = w >> 8;
        }
        __syncthreads();
        for (int i = t; i < segsz; i += 256) csr_src[s0 + i] = stage[i];
    } else {
        for (int i = s0 + t; i < s1; i += 256) {
            int w = bucketed[i];
            int pos = atomicAdd(&cursor[node0 + (w & 255)], 1);
            csr_src[pos] = w >> 8;
        }
    }
}

// K8: packed[v] = one 128B line per node: 8 chunks of {h[4j..4j+3] fp16,
// hws[4j..4j+3] fp16} where hws = dis * (h @ Wgcn). Overwrites bucketed.
__global__ __launch_bounds__(256) void embed2_kernel(
    const float* __restrict__ h, const void* __restrict__ Wgcn,
    const int* __restrict__ rowptr, const int* __restrict__ flagp,
    uint4* __restrict__ packed, int N)
{
    __shared__ float Wg[HN * HN];
    __shared__ float hs[32][HN + 1];
    __shared__ float ws[32][HN + 1];
    const int tid = threadIdx.x;
    const int isbf = flagp[0];
    for (int i = tid; i < HN * HN; i += 256) Wg[i] = ldf(Wgcn, i, isbf);
    const int n0 = blockIdx.x * 32;
    for (int i = tid; i < 32 * HN; i += 256) {
        int n = i >> 5, f = i & 31;
        hs[n][f] = (n0 + n < N) ? h[(size_t)(n0 + n) * HN + f] : 0.f;
    }
    __syncthreads();
    const int f = tid & 31, ns = tid >> 5;
    #pragma unroll
    for (int g = 0; g < 4; ++g) {
        int n = ns + 8 * g, v = n0 + n;
        float acc = 0.f;
        #pragma unroll
        for (int k = 0; k < HN; ++k) acc += hs[n][k] * Wg[k * HN + f];
        float dis = (v < N) ? rsqrtf((float)(rowptr[v + 1] - rowptr[v]) + 1.0f) : 0.f;
        ws[n][f] = dis * acc;
    }
    __syncthreads();
    const int n = tid >> 3, jj = tid & 7, v = n0 + n;
    if (v < N) {
        uint4 w;
        w.x = pack2h(hs[n][4 * jj + 0], hs[n][4 * jj + 1]);
        w.y = pack2h(hs[n][4 * jj + 2], hs[n][4 * jj + 3]);
        w.z = pack2h(ws[n][4 * jj + 0], ws[n][4 * jj + 1]);
        w.w = pack2h(ws[n][4 * jj + 2], ws[n][4 * jj + 3]);
        packed[(size_t)v * 8 + jj] = w;
    }
}

// K9 (passB): fused gather pass, online softmax (log2 domain).
// Neighbor payload = ONE 128B line per edge (fp16 h + fp16 hws), 2x unrolled.
__global__ __launch_bounds__(256) void passB_kernel(
    const float* __restrict__ h, const uint4* __restrict__ packed,
    const int* __restrict__ csr_src, const int* __restrict__ rowptr,
    const void* __restrict__ t, const void* __restrict__ bgcn,
    const int* __restrict__ flagp,
    float* __restrict__ outr, float* __restrict__ outz,
    float* __restrict__ out0_ml, float* __restrict__ denout, int N)
{
    const int tid = threadIdx.x;
    const int lane = tid & 31;
    const int sub = lane >> 3;
    const int j = lane & 7;
    const int v = blockIdx.x * 8 + (tid >> 5);
    if (v >= N) return;
    const int isbf = flagp[0];

    const float4* h4 = (const float4*)h;
    float4 hv = h4[(size_t)v * 8 + j];          // fp32 self (score + rep)
    uint4 sw = packed[(size_t)v * 8 + j];       // self line for wsv (fp16)
    float2 wsv0 = up2(sw.z), wsv1 = up2(sw.w);
    const int s = rowptr[v], e2 = rowptr[v + 1];

    float m = -1e30f, den = 0.f, num = 0.f;     // m in log2 domain
    float ax = 0.f, ay = 0.f, az = 0.f, aw = 0.f;
    int i = s + sub;
    for (; i + 4 < e2; i += 8) {
        int r0 = csr_src[i];
        int r1 = csr_src[i + 4];
        uint4 w0 = packed[(size_t)r0 * 8 + j];
        uint4 w1 = packed[(size_t)r1 * 8 + j];
        float tr0 = ldf(t, r0, isbf);
        float tr1 = ldf(t, r1, isbf);
        float2 h00 = up2(w0.x), h01 = up2(w0.y);
        float2 h10 = up2(w1.x), h11 = up2(w1.y);
        float p0 = hv.x * h00.x + hv.y * h00.y + hv.z * h01.x + hv.w * h01.y;
        float p1 = hv.x * h10.x + hv.y * h10.y + hv.z * h11.x + hv.w * h11.y;
        p0 += __shfl_xor(p0, 1, 32);
        p0 += __shfl_xor(p0, 2, 32);
        p0 += __shfl_xor(p0, 4, 32);
        p1 += __shfl_xor(p1, 1, 32);
        p1 += __shfl_xor(p1, 2, 32);
        p1 += __shfl_xor(p1, 4, 32);
        p0 *= LOG2E; p1 *= LOG2E;
        float2 a00 = up2(w0.z), a01 = up2(w0.w);
        float2 a10 = up2(w1.z), a11 = up2(w1.w);
        ax += a00.x + a10.x; ay += a00.y + a10.y;
        az += a01.x + a11.x; aw += a01.y + a11.y;
        float mn = fmaxf(m, fmaxf(p0, p1));
        float corr = exp2f(m - mn);
        float e0 = exp2f(p0 - mn), e1 = exp2f(p1 - mn);
        den = den * corr + e0 + e1;
        num = num * corr + e0 * tr0 + e1 * tr1;
        m = mn;
    }
    if (i < e2) {
        int r0 = csr_src[i];
        uint4 w0 = packed[(size_t)r0 * 8 + j];
        float tr0 = ldf(t, r0, isbf);
        float2 h00 = up2(w0.x), h01 = up2(w0.y);
        float p0 = hv.x * h00.x + hv.y * h00.y + hv.z * h01.x + hv.w * h01.y;
        p0 += __shfl_xor(p0, 1, 32);
        p0 += __shfl_xor(p0, 2, 32);
        p0 += __shfl_xor(p0, 4, 32);
        p0 *= LOG2E;
        float2 a00 = up2(w0.z), a01 = up2(w0.w);
        ax += a00.x; ay += a00.y; az += a01.x; aw += a01.y;
        float mn = fmaxf(m, p0);
        float corr = exp2f(m - mn);
        float e0 = exp2f(p0 - mn);
        den = den * corr + e0;
        num = num * corr + e0 * tr0;
        m = mn;
    }
    #pragma unroll
    for (int o = 8; o <= 16; o <<= 1) {
        float mo = __shfl_xor(m, o, 32);
        float dno = __shfl_xor(den, o, 32);
        float nmo = __shfl_xor(num, o, 32);
        float mn = fmaxf(m, mo);
        float ca = exp2f(m - mn), cb = exp2f(mo - mn);
        den = den * ca + dno * cb;
        num = num * ca + nmo * cb;
        m = mn;
        ax += __shfl_xor(ax, o, 32);
        ay += __shfl_xor(ay, o, 32);
        az += __shfl_xor(az, o, 32);
        aw += __shfl_xor(aw, o, 32);
    }

    float dv = rsqrtf((float)(e2 - s) + 1.0f);
    float4 rep;
    rep.x = hv.x + fmaxf(dv * (ax + wsv0.x) + ldf(bgcn, 4 * j + 0, isbf), 0.f);
    rep.y = hv.y + fmaxf(dv * (ay + wsv0.y) + ldf(bgcn, 4 * j + 1, isbf), 0.f);
    rep.z = hv.z + fmaxf(dv * (az + wsv1.x) + ldf(bgcn, 4 * j + 2, isbf), 0.f);
    rep.w = hv.w + fmaxf(dv * (aw + wsv1.y) + ldf(bgcn, 4 * j + 3, isbf), 0.f);
    if (sub == 0)
        ((float4*)outr)[(size_t)v * 8 + j] = rep;
    if (lane == 0) {
        outz[v]    = num / fmaxf(den, 1e-37f);
        out0_ml[v] = m;          // log2 domain
        denout[v]  = den;
    }
}

// K10a/K10b: global max over per-node local maxes
__global__ __launch_bounds__(256) void amax1_kernel(
    const float* __restrict__ ml, float* __restrict__ bmax2, int N)
{
    float m = -INFINITY;
    for (int i = blockIdx.x * 256 + threadIdx.x; i < N; i += 256 * 256)
        m = fmaxf(m, ml[i]);
    #pragma unroll
    for (int s = 32; s; s >>= 1) m = fmaxf(m, __shfl_xor(m, s, 64));
    __shared__ float sm[4];
    if ((threadIdx.x & 63) == 0) sm[threadIdx.x >> 6] = m;
    __syncthreads();
    if (threadIdx.x == 0)
        bmax2[blockIdx.x] = fmaxf(fmaxf(sm[0], sm[1]), fmaxf(sm[2], sm[3]));
}
__global__ __launch_bounds__(256) void amax2_kernel(
    const float* __restrict__ bmax2, float* __restrict__ amax)
{
    float m = bmax2[threadIdx.x];
    #pragma unroll
    for (int s = 32; s; s >>= 1) m = fmaxf(m, __shfl_xor(m, s, 64));
    __shared__ float sm[4];
    if ((threadIdx.x & 63) == 0) sm[threadIdx.x >> 6] = m;
    __syncthreads();
    if (threadIdx.x == 0) amax[0] = fmaxf(fmaxf(sm[0], sm[1]), fmaxf(sm[2], sm[3]));
}

// K11: exact epsilon correction (log2 domain) + FF head.
__global__ __launch_bounds__(256) void final_kernel(
    const float* __restrict__ rep_in,
    const void* __restrict__ t, const int* __restrict__ flagp,
    const float* __restrict__ amax, const float* __restrict__ denarr,
    const void* __restrict__ W1, const void* __restrict__ b1,
    const void* __restrict__ W2, const void* __restrict__ b2,
    float* __restrict__ out0, float* __restrict__ outz, int N)
{
    __shared__ float W1s[34 * HN];
    __shared__ float b1s[HN], W2s[HN];
    __shared__ float b2s;
    const int tid = threadIdx.x;
    const int isbf = flagp[0];
    for (int i = tid; i < 34 * HN; i += 256) W1s[i] = ldf(W1, i, isbf);
    if (tid < HN) {
        b1s[tid] = ldf(b1, tid, isbf);
        W2s[tid] = ldf(W2, tid, isbf);
    }
    if (tid == 0) b2s = ldf(b2, 0, isbf);
    __syncthreads();

    const int lane = tid & 31;
    const int v = blockIdx.x * 8 + (tid >> 5);
    if (v >= N) return;

    float rep = rep_in[(size_t)v * HN + lane];
    float ml  = out0[v];
    float den = denarr[v];
    float zh  = outz[v];
    float am  = amax[0];
    float term = (1e-8f / den) * exp2f(am - ml);   // log2-domain stabilizer
    float z = zh / (1.0f + term);
    float tv = ldf(t, v, isbf);

    float acc = b1s[lane] + tv * W1s[32 * HN + lane] + z * W1s[33 * HN + lane];
    #pragma unroll
    for (int k = 0; k < HN; ++k)
        acc += __shfl(rep, k, 32) * W1s[k * HN + lane];
    float f1 = fmaxf(acc, 0.f);
    float o = f1 * W2s[lane];
    #pragma unroll
    for (int m = 16; m; m >>= 1) o += __shfl_xor(o, m, 32);

    if (lane == 0) {
        out0[v] = o + b2s;
        outz[v] = z;
    }
}

extern "C" void kernel_launch(void* const* d_in, const int* in_sizes, int n_in,
                              void* d_out, int out_size, void* d_ws, size_t ws_size,
                              hipStream_t stream)
{
    const int N = out_size / 34;   // out[N] + rep[N*32] + z[N]
    const int E = in_sizes[2];

    const void* x    = d_in[0];
    const void* t    = d_in[1];
    const int* row   = (const int*)d_in[2];
    const int* col   = (const int*)d_in[3];
    const void* Wemb = d_in[4];
    const void* bemb = d_in[5];
    const void* Wgcn = d_in[6];
    const void* bgcn = d_in[7];
    const void* W1   = d_in[8];
    const void* b1   = d_in[9];
    const void* W2   = d_in[10];
    const void* b2   = d_in[11];

    const int B   = (N + 255) >> 8;         // coarse buckets (<=512 for N<=131072)
    const int nsb = (N + 2047) / 2048;      // rowptr-scan chunks
    const int NB1 = (E + CH1 - 1) / CH1;    // phase1 blocks

    // ws: h | hwbuf(bucketed->packed) | csr_src | rowptr | count(cursor->den)
    //     | bucket_cursor | bmax2 | bsum | amax | flag
    char* wsb = (char*)d_ws;
    size_t off = 0;
    float* h        = (float*)(wsb + off); off += (size_t)N * HN * 4;
    size_t hwbytes  = (size_t)N * HN * 4;  // == N*128B packed line region
    if ((size_t)E * 4 > hwbytes) hwbytes = (size_t)E * 4;
    char*  hwreg    = wsb + off;           off += hwbytes;
    int*   csr_src  = (int*)(wsb + off);   off += (size_t)E * 4;
    int*   rowptr   = (int*)(wsb + off);   off += (size_t)(N + 1) * 4;
    int*   count    = (int*)(wsb + off);   off += (size_t)N * 4;
    int*   bucket_cursor = (int*)(wsb + off); off += (size_t)B * 4;
    float* bmax2    = (float*)(wsb + off); off += 256 * 4;
    int*   bsum     = (int*)(wsb + off);   off += (size_t)nsb * 4;
    float* amax     = (float*)(wsb + off); off += 4;
    int*   flag     = (int*)(wsb + off);   off += 4;

    int*   bucketed = (int*)hwreg;         // phase 1..2b
    uint4* packed   = (uint4*)hwreg;       // after phase2b: N x 128B fp16 lines

    hipMemsetAsync(count, 0, (size_t)N * 4, stream);

    detect_kernel<<<1, 64, 0, stream>>>((const unsigned int*)x, flag);
    embed1_kernel<<<(N + 31) / 32, 256, 0, stream>>>(x, Wemb, bemb, flag, h, N);

    degcnt_kernel<<<2048, 256, 0, stream>>>(col, count, E);
    scan1_kernel<<<nsb, 256, 0, stream>>>(count, bsum, N);
    scan2_kernel<<<1, 64, 0, stream>>>(bsum, nsb, rowptr, N, E);
    scan3_kernel<<<nsb, 256, 0, stream>>>(count, bsum, rowptr, bucket_cursor, N);
    phase1_kernel<<<NB1, 512, 0, stream>>>(row, col, bucket_cursor,
                                           bucketed, E, B);
    phase2b_kernel<<<B, 256, 0, stream>>>(bucketed, rowptr, count, csr_src, N);
    embed2_kernel<<<(N + 31) / 32, 256, 0, stream>>>(h, Wgcn, rowptr, flag,
                                                     packed, N);

    float* outp = (float*)d_out;
    float* out0 = outp;
    float* outr = outp + N;
    float* outz = outp + (size_t)N * 33;
    float* den  = (float*)count;   // cursor dead after phase2b

    passB_kernel<<<(N + 7) / 8, 256, 0, stream>>>(
        h, packed, csr_src, rowptr, t, bgcn, flag, outr, outz, out0, den, N);
    amax1_kernel<<<256, 256, 0, stream>>>(out0, bmax2, N);
    amax2_kernel<<<1, 256, 0, stream>>>(bmax2, amax);
    final_kernel<<<(N + 7) / 8, 256, 0, stream>>>(
        outr, t, flag, amax, den, W1, b1, W2, b2, out0, outz, N);
}

// Round 5
// 340.718 us; speedup vs baseline: 1.3755x; 1.3755x over previous
//
#include <hip/hip_runtime.h>
#include <hip/hip_bf16.h>
#include <hip/hip_fp16.h>

static constexpr int HN = 32;     // Hemb == Hgcn == 32
static constexpr int NIN = 128;
static constexpr int CH1 = 8192;  // edges per phase-1 block
static constexpr int CAP2 = 16384; // LDS stage capacity (ints) in phase 2
static constexpr float LOG2E = 1.4426950408889634f;

__device__ __forceinline__ float bf2f(unsigned short u) {
    union { unsigned int i; float f; } v;
    v.i = ((unsigned int)u) << 16;
    return v.f;
}
__device__ __forceinline__ float ldf(const void* p, size_t i, int isbf) {
    return isbf ? bf2f(((const unsigned short*)p)[i]) : ((const float*)p)[i];
}
__device__ __forceinline__ unsigned int pack2h(float a, float b) {
    unsigned short ua = __half_as_ushort(__float2half_rn(a));
    unsigned short ub = __half_as_ushort(__float2half_rn(b));
    return (unsigned int)ua | ((unsigned int)ub << 16);
}
__device__ __forceinline__ float2 up2(unsigned int u) {
    __half2 h2;
    *reinterpret_cast<unsigned int*>(&h2) = u;
    return __half22float2(h2);
}

// K0: bf16-vs-fp32 input sniff (validated fp32; kept as insurance).
__global__ void detect_kernel(const unsigned int* __restrict__ xw,
                              int* __restrict__ flag)
{
    int lane = threadIdx.x;          // 64 threads
    int hits = 0;
    #pragma unroll
    for (int k = 0; k < 2; ++k) {
        unsigned int w = xw[lane + 64 * k];
        float a = bf2f((unsigned short)(w & 0xFFFFu));
        float aa = fabsf(a);
        if (a == 0.0f || (aa >= 0.000244140625f && aa <= 32.0f)) hits++;
    }
    #pragma unroll
    for (int m = 32; m; m >>= 1) hits += __shfl_xor(hits, m, 64);
    if (lane == 0) flag[0] = (hits >= 64) ? 1 : 0;
}

// K1: h = relu(x @ Wemb + bemb) -> fp32.
__global__ __launch_bounds__(256) void embed1_kernel(
    const void* __restrict__ x,
    const void* __restrict__ Wemb,
    const void* __restrict__ bemb,
    const int* __restrict__ flagp,
    float* __restrict__ h, int N)
{
    __shared__ float We[NIN * HN];
    __shared__ float be[HN];
    __shared__ float xs[32][NIN];
    const int tid = threadIdx.x;
    const int isbf = flagp[0];

    for (int i = tid; i < NIN * HN; i += 256) We[i] = ldf(Wemb, i, isbf);
    if (tid < HN) be[tid] = ldf(bemb, tid, isbf);

    const int n0 = blockIdx.x * 32;
    if (isbf) {
        const ushort4* x4 = (const ushort4*)((const unsigned short*)x + (size_t)n0 * NIN);
        for (int i = tid; i < 32 * (NIN / 4); i += 256) {
            ushort4 u = x4[i];
            int base = i * 4, n = base >> 7, k = base & (NIN - 1);
            xs[n][k] = bf2f(u.x); xs[n][k + 1] = bf2f(u.y);
            xs[n][k + 2] = bf2f(u.z); xs[n][k + 3] = bf2f(u.w);
        }
    } else {
        const float4* x4 = (const float4*)((const float*)x + (size_t)n0 * NIN);
        for (int i = tid; i < 32 * (NIN / 4); i += 256) {
            float4 u = x4[i];
            int base = i * 4, n = base >> 7, k = base & (NIN - 1);
            xs[n][k] = u.x; xs[n][k + 1] = u.y;
            xs[n][k + 2] = u.z; xs[n][k + 3] = u.w;
        }
    }
    __syncthreads();

    const int f = tid & 31, ns = tid >> 5;
    float a0 = be[f], a1 = be[f], a2 = be[f], a3 = be[f];
    #pragma unroll 8
    for (int k = 0; k < NIN; ++k) {
        float w = We[k * HN + f];
        a0 += xs[ns +  0][k] * w;
        a1 += xs[ns +  8][k] * w;
        a2 += xs[ns + 16][k] * w;
        a3 += xs[ns + 24][k] * w;
    }
    if (n0 + ns      < N) h[(size_t)(n0 + ns     ) * HN + f] = fmaxf(a0, 0.f);
    if (n0 + ns +  8 < N) h[(size_t)(n0 + ns +  8) * HN + f] = fmaxf(a1, 0.f);
    if (n0 + ns + 16 < N) h[(size_t)(n0 + ns + 16) * HN + f] = fmaxf(a2, 0.f);
    if (n0 + ns + 24 < N) h[(size_t)(n0 + ns + 24) * HN + f] = fmaxf(a3, 0.f);
}

// K2: coarse bucket histogram (bucket = col>>8), LDS-aggregated.
// (degcnt via global atomics was 130us / 100MB atomic write traffic — reverted.)
__global__ __launch_bounds__(512) void bhist_kernel(
    const int* __restrict__ col, int* __restrict__ bucket_cnt, int E, int B)
{
    __shared__ int hist[512];
    const int t = threadIdx.x;
    const int e0 = blockIdx.x * CH1;
    for (int i = t; i < B; i += 512) hist[i] = 0;
    __syncthreads();
    #pragma unroll
    for (int k = 0; k < CH1 / 512; ++k) {
        int e = e0 + k * 512 + t;
        if (e < E) atomicAdd(&hist[col[e] >> 8], 1);
    }
    __syncthreads();
    for (int i = t; i < B; i += 512)
        if (hist[i]) atomicAdd(&bucket_cnt[i], hist[i]);
}

// K3: exclusive scan of bucket counts (B <= 512); init cursors; rowptr[N]=E.
__global__ __launch_bounds__(512) void bscan_kernel(
    const int* __restrict__ bucket_cnt, int* __restrict__ bucket_base,
    int* __restrict__ bucket_cursor, int* __restrict__ rowptr,
    int B, int N, int E)
{
    __shared__ int sc[512];
    __shared__ int orig[512];
    const int t = threadIdx.x;
    int v0 = (t < B) ? bucket_cnt[t] : 0;
    sc[t] = v0; orig[t] = v0;
    __syncthreads();
    for (int o = 1; o < 512; o <<= 1) {
        int v = (t >= o) ? sc[t - o] : 0;
        __syncthreads();
        sc[t] += v;
        __syncthreads();
    }
    if (t < B) {
        int ex = sc[t] - orig[t];
        bucket_base[t] = ex;
        bucket_cursor[t] = ex;
    }
    if (t == 0) { bucket_base[B] = E; rowptr[N] = E; }
}

// K4 (phase1): bucketize edges with LDS reorder -> semi-coalesced writes of
// packed words (row<<8 | col&255) grouped by bucket. bucket = col>>8.
__global__ __launch_bounds__(512) void phase1_kernel(
    const int* __restrict__ row, const int* __restrict__ col,
    int* __restrict__ bucket_cursor, int* __restrict__ bucketed, int E, int B)
{
    __shared__ int hist[512];
    __shared__ int sc[512];
    __shared__ int cnt[512];
    __shared__ int gbase[512];
    __shared__ int word[CH1];
    __shared__ int dst[CH1];
    const int t = threadIdx.x;
    const int e0 = blockIdx.x * CH1;
    const int M = (E - e0 < CH1) ? (E - e0) : CH1;

    for (int i = t; i < B; i += 512) { hist[i] = 0; cnt[i] = 0; }
    __syncthreads();
    #pragma unroll
    for (int k = 0; k < CH1 / 512; ++k) {
        int e = e0 + k * 512 + t;
        if (e < E) atomicAdd(&hist[col[e] >> 8], 1);
    }
    __syncthreads();
    sc[t] = (t < B) ? hist[t] : 0;
    __syncthreads();
    for (int o = 1; o < 512; o <<= 1) {
        int v = (t >= o) ? sc[t - o] : 0;
        __syncthreads();
        sc[t] += v;
        __syncthreads();
    }
    if (t < B && hist[t])
        gbase[t] = atomicAdd(&bucket_cursor[t], hist[t]);
    __syncthreads();
    #pragma unroll
    for (int k = 0; k < CH1 / 512; ++k) {
        int e = e0 + k * 512 + t;
        if (e < E) {
            int c = col[e], r = row[e];
            int b = c >> 8;
            int lr = atomicAdd(&cnt[b], 1);
            int p = sc[b] - hist[b] + lr;     // exclusive scan + rank
            word[p] = (r << 8) | (c & 255);
            dst[p] = gbase[b] + lr;
        }
    }
    __syncthreads();
    for (int i = t; i < M; i += 512)
        bucketed[dst[i]] = word[i];
}

// K5 (phase2, fused): one block per bucket. Pass 1 counts per-node degrees
// in LDS; block-scan gives local exclusive offsets -> rowptr written directly
// (rowptr[node0+t] = bucket_base[b] + loc[t]). Pass 2 places edges via LDS
// cursors (staged+coalesced when segment fits CAP2). Replaces phase2a +
// scan1 + scan2 + scan3 + old phase2b.
__global__ __launch_bounds__(256) void phase2_kernel(
    const int* __restrict__ bucketed, const int* __restrict__ bucket_base,
    int* __restrict__ rowptr, int* __restrict__ csr_src, int N)
{
    __shared__ int stage[CAP2];
    __shared__ int cnt[256];
    __shared__ int sc[256];
    __shared__ int loc[256];
    const int t = threadIdx.x, b = blockIdx.x;
    const int node0 = b << 8;
    const int s0 = bucket_base[b], s1 = bucket_base[b + 1];
    const int segsz = s1 - s0;
    cnt[t] = 0;
    __syncthreads();
    for (int i = s0 + t; i < s1; i += 256)
        atomicAdd(&cnt[bucketed[i] & 255], 1);
    __syncthreads();
    int c = cnt[t];
    sc[t] = c;
    __syncthreads();
    for (int o = 1; o < 256; o <<= 1) {
        int v = (t >= o) ? sc[t - o] : 0;
        __syncthreads();
        sc[t] += v;
        __syncthreads();
    }
    int ex = sc[t] - c;                 // local exclusive offset
    loc[t] = ex;
    if (node0 + t < N) rowptr[node0 + t] = s0 + ex;
    cnt[t] = 0;                         // reuse as placement cursor
    __syncthreads();
    if (segsz <= CAP2) {
        for (int i = s0 + t; i < s1; i += 256) {
            int w = bucketed[i];
            int lc = w & 255;
            int off = loc[lc] + atomicAdd(&cnt[lc], 1);
            stage[off] = w >> 8;
        }
        __syncthreads();
        for (int i = t; i < segsz; i += 256) csr_src[s0 + i] = stage[i];
    } else {
        for (int i = s0 + t; i < s1; i += 256) {
            int w = bucketed[i];
            int lc = w & 255;
            int off = loc[lc] + atomicAdd(&cnt[lc], 1);
            csr_src[s0 + off] = w >> 8;
        }
    }
}

// K8: packed[v] = one 128B line per node: 8 chunks of {h[4j..4j+3] fp16,
// hws[4j..4j+3] fp16} where hws = dis * (h @ Wgcn). Overwrites bucketed.
__global__ __launch_bounds__(256) void embed2_kernel(
    const float* __restrict__ h, const void* __restrict__ Wgcn,
    const int* __restrict__ rowptr, const int* __restrict__ flagp,
    uint4* __restrict__ packed, int N)
{
    __shared__ float Wg[HN * HN];
    __shared__ float hs[32][HN + 1];
    __shared__ float ws[32][HN + 1];
    const int tid = threadIdx.x;
    const int isbf = flagp[0];
    for (int i = tid; i < HN * HN; i += 256) Wg[i] = ldf(Wgcn, i, isbf);
    const int n0 = blockIdx.x * 32;
    for (int i = tid; i < 32 * HN; i += 256) {
        int n = i >> 5, f = i & 31;
        hs[n][f] = (n0 + n < N) ? h[(size_t)(n0 + n) * HN + f] : 0.f;
    }
    __syncthreads();
    const int f = tid & 31, ns = tid >> 5;
    #pragma unroll
    for (int g = 0; g < 4; ++g) {
        int n = ns + 8 * g, v = n0 + n;
        float acc = 0.f;
        #pragma unroll
        for (int k = 0; k < HN; ++k) acc += hs[n][k] * Wg[k * HN + f];
        float dis = (v < N) ? rsqrtf((float)(rowptr[v + 1] - rowptr[v]) + 1.0f) : 0.f;
        ws[n][f] = dis * acc;
    }
    __syncthreads();
    const int n = tid >> 3, jj = tid & 7, v = n0 + n;
    if (v < N) {
        uint4 w;
        w.x = pack2h(hs[n][4 * jj + 0], hs[n][4 * jj + 1]);
        w.y = pack2h(hs[n][4 * jj + 2], hs[n][4 * jj + 3]);
        w.z = pack2h(ws[n][4 * jj + 0], ws[n][4 * jj + 1]);
        w.w = pack2h(ws[n][4 * jj + 2], ws[n][4 * jj + 3]);
        packed[(size_t)v * 8 + jj] = w;
    }
}

// K9 (passB): fused gather pass, online softmax (log2 domain).
// Neighbor payload = ONE 128B line per edge (fp16 h + fp16 hws), 2x unrolled.
__global__ __launch_bounds__(256) void passB_kernel(
    const float* __restrict__ h, const uint4* __restrict__ packed,
    const int* __restrict__ csr_src, const int* __restrict__ rowptr,
    const void* __restrict__ t, const void* __restrict__ bgcn,
    const int* __restrict__ flagp,
    float* __restrict__ outr, float* __restrict__ outz,
    float* __restrict__ out0_ml, float* __restrict__ denout, int N)
{
    const int tid = threadIdx.x;
    const int lane = tid & 31;
    const int sub = lane >> 3;
    const int j = lane & 7;
    const int v = blockIdx.x * 8 + (tid >> 5);
    if (v >= N) return;
    const int isbf = flagp[0];

    const float4* h4 = (const float4*)h;
    float4 hv = h4[(size_t)v * 8 + j];          // fp32 self (score + rep)
    uint4 sw = packed[(size_t)v * 8 + j];       // self line for wsv (fp16)
    float2 wsv0 = up2(sw.z), wsv1 = up2(sw.w);
    const int s = rowptr[v], e2 = rowptr[v + 1];

    float m = -1e30f, den = 0.f, num = 0.f;     // m in log2 domain
    float ax = 0.f, ay = 0.f, az = 0.f, aw = 0.f;
    int i = s + sub;
    for (; i + 4 < e2; i += 8) {
        int r0 = csr_src[i];
        int r1 = csr_src[i + 4];
        uint4 w0 = packed[(size_t)r0 * 8 + j];
        uint4 w1 = packed[(size_t)r1 * 8 + j];
        float tr0 = ldf(t, r0, isbf);
        float tr1 = ldf(t, r1, isbf);
        float2 h00 = up2(w0.x), h01 = up2(w0.y);
        float2 h10 = up2(w1.x), h11 = up2(w1.y);
        float p0 = hv.x * h00.x + hv.y * h00.y + hv.z * h01.x + hv.w * h01.y;
        float p1 = hv.x * h10.x + hv.y * h10.y + hv.z * h11.x + hv.w * h11.y;
        p0 += __shfl_xor(p0, 1, 32);
        p0 += __shfl_xor(p0, 2, 32);
        p0 += __shfl_xor(p0, 4, 32);
        p1 += __shfl_xor(p1, 1, 32);
        p1 += __shfl_xor(p1, 2, 32);
        p1 += __shfl_xor(p1, 4, 32);
        p0 *= LOG2E; p1 *= LOG2E;
        float2 a00 = up2(w0.z), a01 = up2(w0.w);
        float2 a10 = up2(w1.z), a11 = up2(w1.w);
        ax += a00.x + a10.x; ay += a00.y + a10.y;
        az += a01.x + a11.x; aw += a01.y + a11.y;
        float mn = fmaxf(m, fmaxf(p0, p1));
        float corr = exp2f(m - mn);
        float e0 = exp2f(p0 - mn), e1 = exp2f(p1 - mn);
        den = den * corr + e0 + e1;
        num = num * corr + e0 * tr0 + e1 * tr1;
        m = mn;
    }
    if (i < e2) {
        int r0 = csr_src[i];
        uint4 w0 = packed[(size_t)r0 * 8 + j];
        float tr0 = ldf(t, r0, isbf);
        float2 h00 = up2(w0.x), h01 = up2(w0.y);
        float p0 = hv.x * h00.x + hv.y * h00.y + hv.z * h01.x + hv.w * h01.y;
        p0 += __shfl_xor(p0, 1, 32);
        p0 += __shfl_xor(p0, 2, 32);
        p0 += __shfl_xor(p0, 4, 32);
        p0 *= LOG2E;
        float2 a00 = up2(w0.z), a01 = up2(w0.w);
        ax += a00.x; ay += a00.y; az += a01.x; aw += a01.y;
        float mn = fmaxf(m, p0);
        float corr = exp2f(m - mn);
        float e0 = exp2f(p0 - mn);
        den = den * corr + e0;
        num = num * corr + e0 * tr0;
        m = mn;
    }
    #pragma unroll
    for (int o = 8; o <= 16; o <<= 1) {
        float mo = __shfl_xor(m, o, 32);
        float dno = __shfl_xor(den, o, 32);
        float nmo = __shfl_xor(num, o, 32);
        float mn = fmaxf(m, mo);
        float ca = exp2f(m - mn), cb = exp2f(mo - mn);
        den = den * ca + dno * cb;
        num = num * ca + nmo * cb;
        m = mn;
        ax += __shfl_xor(ax, o, 32);
        ay += __shfl_xor(ay, o, 32);
        az += __shfl_xor(az, o, 32);
        aw += __shfl_xor(aw, o, 32);
    }

    float dv = rsqrtf((float)(e2 - s) + 1.0f);
    float4 rep;
    rep.x = hv.x + fmaxf(dv * (ax + wsv0.x) + ldf(bgcn, 4 * j + 0, isbf), 0.f);
    rep.y = hv.y + fmaxf(dv * (ay + wsv0.y) + ldf(bgcn, 4 * j + 1, isbf), 0.f);
    rep.z = hv.z + fmaxf(dv * (az + wsv1.x) + ldf(bgcn, 4 * j + 2, isbf), 0.f);
    rep.w = hv.w + fmaxf(dv * (aw + wsv1.y) + ldf(bgcn, 4 * j + 3, isbf), 0.f);
    if (sub == 0)
        ((float4*)outr)[(size_t)v * 8 + j] = rep;
    if (lane == 0) {
        outz[v]    = num / fmaxf(den, 1e-37f);
        out0_ml[v] = m;          // log2 domain
        denout[v]  = den;
    }
}

// K10a/K10b: global max over per-node local maxes
__global__ __launch_bounds__(256) void amax1_kernel(
    const float* __restrict__ ml, float* __restrict__ bmax2, int N)
{
    float m = -INFINITY;
    for (int i = blockIdx.x * 256 + threadIdx.x; i < N; i += 256 * 256)
        m = fmaxf(m, ml[i]);
    #pragma unroll
    for (int s = 32; s; s >>= 1) m = fmaxf(m, __shfl_xor(m, s, 64));
    __shared__ float sm[4];
    if ((threadIdx.x & 63) == 0) sm[threadIdx.x >> 6] = m;
    __syncthreads();
    if (threadIdx.x == 0)
        bmax2[blockIdx.x] = fmaxf(fmaxf(sm[0], sm[1]), fmaxf(sm[2], sm[3]));
}
__global__ __launch_bounds__(256) void amax2_kernel(
    const float* __restrict__ bmax2, float* __restrict__ amax)
{
    float m = bmax2[threadIdx.x];
    #pragma unroll
    for (int s = 32; s; s >>= 1) m = fmaxf(m, __shfl_xor(m, s, 64));
    __shared__ float sm[4];
    if ((threadIdx.x & 63) == 0) sm[threadIdx.x >> 6] = m;
    __syncthreads();
    if (threadIdx.x == 0) amax[0] = fmaxf(fmaxf(sm[0], sm[1]), fmaxf(sm[2], sm[3]));
}

// K11: exact epsilon correction (log2 domain) + FF head.
__global__ __launch_bounds__(256) void final_kernel(
    const float* __restrict__ rep_in,
    const void* __restrict__ t, const int* __restrict__ flagp,
    const float* __restrict__ amax, const float* __restrict__ denarr,
    const void* __restrict__ W1, const void* __restrict__ b1,
    const void* __restrict__ W2, const void* __restrict__ b2,
    float* __restrict__ out0, float* __restrict__ outz, int N)
{
    __shared__ float W1s[34 * HN];
    __shared__ float b1s[HN], W2s[HN];
    __shared__ float b2s;
    const int tid = threadIdx.x;
    const int isbf = flagp[0];
    for (int i = tid; i < 34 * HN; i += 256) W1s[i] = ldf(W1, i, isbf);
    if (tid < HN) {
        b1s[tid] = ldf(b1, tid, isbf);
        W2s[tid] = ldf(W2, tid, isbf);
    }
    if (tid == 0) b2s = ldf(b2, 0, isbf);
    __syncthreads();

    const int lane = tid & 31;
    const int v = blockIdx.x * 8 + (tid >> 5);
    if (v >= N) return;

    float rep = rep_in[(size_t)v * HN + lane];
    float ml  = out0[v];
    float den = denarr[v];
    float zh  = outz[v];
    float am  = amax[0];
    float term = (1e-8f / den) * exp2f(am - ml);   // log2-domain stabilizer
    float z = zh / (1.0f + term);
    float tv = ldf(t, v, isbf);

    float acc = b1s[lane] + tv * W1s[32 * HN + lane] + z * W1s[33 * HN + lane];
    #pragma unroll
    for (int k = 0; k < HN; ++k)
        acc += __shfl(rep, k, 32) * W1s[k * HN + lane];
    float f1 = fmaxf(acc, 0.f);
    float o = f1 * W2s[lane];
    #pragma unroll
    for (int m = 16; m; m >>= 1) o += __shfl_xor(o, m, 32);

    if (lane == 0) {
        out0[v] = o + b2s;
        outz[v] = z;
    }
}

extern "C" void kernel_launch(void* const* d_in, const int* in_sizes, int n_in,
                              void* d_out, int out_size, void* d_ws, size_t ws_size,
                              hipStream_t stream)
{
    const int N = out_size / 34;   // out[N] + rep[N*32] + z[N]
    const int E = in_sizes[2];

    const void* x    = d_in[0];
    const void* t    = d_in[1];
    const int* row   = (const int*)d_in[2];
    const int* col   = (const int*)d_in[3];
    const void* Wemb = d_in[4];
    const void* bemb = d_in[5];
    const void* Wgcn = d_in[6];
    const void* bgcn = d_in[7];
    const void* W1   = d_in[8];
    const void* b1   = d_in[9];
    const void* W2   = d_in[10];
    const void* b2   = d_in[11];

    const int B   = (N + 255) >> 8;         // coarse buckets (<=512 for N<=131072)
    const int NB1 = (E + CH1 - 1) / CH1;    // phase1/bhist blocks

    // ws: h | hwbuf(bucketed->packed) | csr_src | rowptr | den
    //     | bucket_cnt | bucket_base | bucket_cursor | bmax2 | amax | flag
    char* wsb = (char*)d_ws;
    size_t off = 0;
    float* h        = (float*)(wsb + off); off += (size_t)N * HN * 4;
    size_t hwbytes  = (size_t)N * HN * 4;  // == N*128B packed line region
    if ((size_t)E * 4 > hwbytes) hwbytes = (size_t)E * 4;
    char*  hwreg    = wsb + off;           off += hwbytes;
    int*   csr_src  = (int*)(wsb + off);   off += (size_t)E * 4;
    int*   rowptr   = (int*)(wsb + off);   off += (size_t)(N + 1) * 4;
    float* den      = (float*)(wsb + off); off += (size_t)N * 4;
    int*   bucket_cnt    = (int*)(wsb + off); off += (size_t)B * 4;
    int*   bucket_base   = (int*)(wsb + off); off += (size_t)(B + 1) * 4;
    int*   bucket_cursor = (int*)(wsb + off); off += (size_t)B * 4;
    float* bmax2    = (float*)(wsb + off); off += 256 * 4;
    float* amax     = (float*)(wsb + off); off += 4;
    int*   flag     = (int*)(wsb + off);   off += 4;

    int*   bucketed = (int*)hwreg;         // phase 1..2
    uint4* packed   = (uint4*)hwreg;       // after phase2: N x 128B fp16 lines

    hipMemsetAsync(bucket_cnt, 0, (size_t)B * 4, stream);

    detect_kernel<<<1, 64, 0, stream>>>((const unsigned int*)x, flag);
    embed1_kernel<<<(N + 31) / 32, 256, 0, stream>>>(x, Wemb, bemb, flag, h, N);

    bhist_kernel<<<NB1, 512, 0, stream>>>(col, bucket_cnt, E, B);
    bscan_kernel<<<1, 512, 0, stream>>>(bucket_cnt, bucket_base,
                                        bucket_cursor, rowptr, B, N, E);
    phase1_kernel<<<NB1, 512, 0, stream>>>(row, col, bucket_cursor,
                                           bucketed, E, B);
    phase2_kernel<<<B, 256, 0, stream>>>(bucketed, bucket_base, rowptr,
                                         csr_src, N);
    embed2_kernel<<<(N + 31) / 32, 256, 0, stream>>>(h, Wgcn, rowptr, flag,
                                                     packed, N);

    float* outp = (float*)d_out;
    float* out0 = outp;
    float* outr = outp + N;
    float* outz = outp + (size_t)N * 33;

    passB_kernel<<<(N + 7) / 8, 256, 0, stream>>>(
        h, packed, csr_src, rowptr, t, bgcn, flag, outr, outz, out0, den, N);
    amax1_kernel<<<256, 256, 0, stream>>>(out0, bmax2, N);
    amax2_kernel<<<1, 256, 0, stream>>>(bmax2, amax);
    final_kernel<<<(N + 7) / 8, 256, 0, stream>>>(
        outr, t, flag, amax, den, W1, b1, W2, b2, out0, outz, N);
}

// Round 6
// 337.550 us; speedup vs baseline: 1.3884x; 1.0094x over previous
//
#include <hip/hip_runtime.h>
#include <hip/hip_bf16.h>
#include <hip/hip_fp16.h>

static constexpr int HN = 32;     // Hemb == Hgcn == 32
static constexpr int NIN = 128;
static constexpr int CH1 = 8192;  // edges per phase-1 block
static constexpr int CAP2 = 16384; // LDS stage capacity (ints) in phase 2
// sqrt(log2(e)): folded into packed fp16 h so the score dot is in exp2 domain.
static constexpr float SQRT_LOG2E = 1.2011224087864498f;

typedef _Float16 h2v __attribute__((ext_vector_type(2)));

__device__ __forceinline__ float bf2f(unsigned short u) {
    union { unsigned int i; float f; } v;
    v.i = ((unsigned int)u) << 16;
    return v.f;
}
__device__ __forceinline__ float ldf(const void* p, size_t i, int isbf) {
    return isbf ? bf2f(((const unsigned short*)p)[i]) : ((const float*)p)[i];
}
__device__ __forceinline__ unsigned int pack2h(float a, float b) {
    unsigned short ua = __half_as_ushort(__float2half_rn(a));
    unsigned short ub = __half_as_ushort(__float2half_rn(b));
    return (unsigned int)ua | ((unsigned int)ub << 16);
}
__device__ __forceinline__ float2 up2(unsigned int u) {
    __half2 h2;
    *reinterpret_cast<unsigned int*>(&h2) = u;
    return __half22float2(h2);
}
// packed-fp16 2-way dot-accumulate (v_dot2_f32_f16). Pure VALU — cannot
// fault; round-2 crash was the misaligned int4 col load, not this.
__device__ __forceinline__ float fd2(unsigned int a, unsigned int b, float c) {
#if __has_builtin(__builtin_amdgcn_fdot2)
    return __builtin_amdgcn_fdot2(__builtin_bit_cast(h2v, a),
                                  __builtin_bit_cast(h2v, b), c, false);
#else
    float2 fa = up2(a), fb = up2(b);
    return c + fa.x * fb.x + fa.y * fb.y;
#endif
}

// K1: h = relu(x @ Wemb + bemb) -> fp32.
__global__ __launch_bounds__(256) void embed1_kernel(
    const void* __restrict__ x,
    const void* __restrict__ Wemb,
    const void* __restrict__ bemb,
    const int* __restrict__ flagp,
    float* __restrict__ h, int N)
{
    __shared__ float We[NIN * HN];
    __shared__ float be[HN];
    __shared__ float xs[32][NIN];
    const int tid = threadIdx.x;
    const int isbf = flagp[0];

    for (int i = tid; i < NIN * HN; i += 256) We[i] = ldf(Wemb, i, isbf);
    if (tid < HN) be[tid] = ldf(bemb, tid, isbf);

    const int n0 = blockIdx.x * 32;
    if (isbf) {
        const ushort4* x4 = (const ushort4*)((const unsigned short*)x + (size_t)n0 * NIN);
        for (int i = tid; i < 32 * (NIN / 4); i += 256) {
            ushort4 u = x4[i];
            int base = i * 4, n = base >> 7, k = base & (NIN - 1);
            xs[n][k] = bf2f(u.x); xs[n][k + 1] = bf2f(u.y);
            xs[n][k + 2] = bf2f(u.z); xs[n][k + 3] = bf2f(u.w);
        }
    } else {
        const float4* x4 = (const float4*)((const float*)x + (size_t)n0 * NIN);
        for (int i = tid; i < 32 * (NIN / 4); i += 256) {
            float4 u = x4[i];
            int base = i * 4, n = base >> 7, k = base & (NIN - 1);
            xs[n][k] = u.x; xs[n][k + 1] = u.y;
            xs[n][k + 2] = u.z; xs[n][k + 3] = u.w;
        }
    }
    __syncthreads();

    const int f = tid & 31, ns = tid >> 5;
    float a0 = be[f], a1 = be[f], a2 = be[f], a3 = be[f];
    #pragma unroll 8
    for (int k = 0; k < NIN; ++k) {
        float w = We[k * HN + f];
        a0 += xs[ns +  0][k] * w;
        a1 += xs[ns +  8][k] * w;
        a2 += xs[ns + 16][k] * w;
        a3 += xs[ns + 24][k] * w;
    }
    if (n0 + ns      < N) h[(size_t)(n0 + ns     ) * HN + f] = fmaxf(a0, 0.f);
    if (n0 + ns +  8 < N) h[(size_t)(n0 + ns +  8) * HN + f] = fmaxf(a1, 0.f);
    if (n0 + ns + 16 < N) h[(size_t)(n0 + ns + 16) * HN + f] = fmaxf(a2, 0.f);
    if (n0 + ns + 24 < N) h[(size_t)(n0 + ns + 24) * HN + f] = fmaxf(a3, 0.f);
}

// K2: coarse bucket histogram (bucket = col>>8), LDS-aggregated.
// Block 0 lanes 0-63 additionally run the bf16-vs-fp32 input sniff (fused
// former detect_kernel; saves one launch).
__global__ __launch_bounds__(512) void bhist_kernel(
    const int* __restrict__ col, int* __restrict__ bucket_cnt, int E, int B,
    const unsigned int* __restrict__ xw, int* __restrict__ flag)
{
    __shared__ int hist[512];
    const int t = threadIdx.x;
    const int e0 = blockIdx.x * CH1;
    for (int i = t; i < B; i += 512) hist[i] = 0;
    if (blockIdx.x == 0 && t < 64) {
        int hits = 0;
        #pragma unroll
        for (int k = 0; k < 2; ++k) {
            unsigned int w = xw[t + 64 * k];
            float a = bf2f((unsigned short)(w & 0xFFFFu));
            float aa = fabsf(a);
            if (a == 0.0f || (aa >= 0.000244140625f && aa <= 32.0f)) hits++;
        }
        #pragma unroll
        for (int m = 32; m; m >>= 1) hits += __shfl_xor(hits, m, 64);
        if (t == 0) flag[0] = (hits >= 64) ? 1 : 0;
    }
    __syncthreads();
    #pragma unroll
    for (int k = 0; k < CH1 / 512; ++k) {
        int e = e0 + k * 512 + t;
        if (e < E) atomicAdd(&hist[col[e] >> 8], 1);
    }
    __syncthreads();
    for (int i = t; i < B; i += 512)
        if (hist[i]) atomicAdd(&bucket_cnt[i], hist[i]);
}

// K3: exclusive scan of bucket counts (B <= 512); init cursors; rowptr[N]=E.
__global__ __launch_bounds__(512) void bscan_kernel(
    const int* __restrict__ bucket_cnt, int* __restrict__ bucket_base,
    int* __restrict__ bucket_cursor, int* __restrict__ rowptr,
    int B, int N, int E)
{
    __shared__ int sc[512];
    __shared__ int orig[512];
    const int t = threadIdx.x;
    int v0 = (t < B) ? bucket_cnt[t] : 0;
    sc[t] = v0; orig[t] = v0;
    __syncthreads();
    for (int o = 1; o < 512; o <<= 1) {
        int v = (t >= o) ? sc[t - o] : 0;
        __syncthreads();
        sc[t] += v;
        __syncthreads();
    }
    if (t < B) {
        int ex = sc[t] - orig[t];
        bucket_base[t] = ex;
        bucket_cursor[t] = ex;
    }
    if (t == 0) { bucket_base[B] = E; rowptr[N] = E; }
}

// K4 (phase1): bucketize edges with LDS reorder -> semi-coalesced writes of
// packed words (row<<8 | col&255) grouped by bucket. bucket = col>>8.
__global__ __launch_bounds__(512) void phase1_kernel(
    const int* __restrict__ row, const int* __restrict__ col,
    int* __restrict__ bucket_cursor, int* __restrict__ bucketed, int E, int B)
{
    __shared__ int hist[512];
    __shared__ int sc[512];
    __shared__ int cnt[512];
    __shared__ int gbase[512];
    __shared__ int word[CH1];
    __shared__ int dst[CH1];
    const int t = threadIdx.x;
    const int e0 = blockIdx.x * CH1;
    const int M = (E - e0 < CH1) ? (E - e0) : CH1;

    for (int i = t; i < B; i += 512) { hist[i] = 0; cnt[i] = 0; }
    __syncthreads();
    #pragma unroll
    for (int k = 0; k < CH1 / 512; ++k) {
        int e = e0 + k * 512 + t;
        if (e < E) atomicAdd(&hist[col[e] >> 8], 1);
    }
    __syncthreads();
    sc[t] = (t < B) ? hist[t] : 0;
    __syncthreads();
    for (int o = 1; o < 512; o <<= 1) {
        int v = (t >= o) ? sc[t - o] : 0;
        __syncthreads();
        sc[t] += v;
        __syncthreads();
    }
    if (t < B && hist[t])
        gbase[t] = atomicAdd(&bucket_cursor[t], hist[t]);
    __syncthreads();
    #pragma unroll
    for (int k = 0; k < CH1 / 512; ++k) {
        int e = e0 + k * 512 + t;
        if (e < E) {
            int c = col[e], r = row[e];
            int b = c >> 8;
            int lr = atomicAdd(&cnt[b], 1);
            int p = sc[b] - hist[b] + lr;     // exclusive scan + rank
            word[p] = (r << 8) | (c & 255);
            dst[p] = gbase[b] + lr;
        }
    }
    __syncthreads();
    for (int i = t; i < M; i += 512)
        bucketed[dst[i]] = word[i];
}

// K5 (phase2, fused): one block per bucket. Pass 1 counts per-node degrees
// in LDS; block-scan gives local exclusive offsets -> rowptr written directly.
// Pass 2 places edges via LDS cursors (staged+coalesced when fits CAP2).
__global__ __launch_bounds__(256) void phase2_kernel(
    const int* __restrict__ bucketed, const int* __restrict__ bucket_base,
    int* __restrict__ rowptr, int* __restrict__ csr_src, int N)
{
    __shared__ int stage[CAP2];
    __shared__ int cnt[256];
    __shared__ int sc[256];
    __shared__ int loc[256];
    const int t = threadIdx.x, b = blockIdx.x;
    const int node0 = b << 8;
    const int s0 = bucket_base[b], s1 = bucket_base[b + 1];
    const int segsz = s1 - s0;
    cnt[t] = 0;
    __syncthreads();
    for (int i = s0 + t; i < s1; i += 256)
        atomicAdd(&cnt[bucketed[i] & 255], 1);
    __syncthreads();
    int c = cnt[t];
    sc[t] = c;
    __syncthreads();
    for (int o = 1; o < 256; o <<= 1) {
        int v = (t >= o) ? sc[t - o] : 0;
        __syncthreads();
        sc[t] += v;
        __syncthreads();
    }
    int ex = sc[t] - c;                 // local exclusive offset
    loc[t] = ex;
    if (node0 + t < N) rowptr[node0 + t] = s0 + ex;
    cnt[t] = 0;                         // reuse as placement cursor
    __syncthreads();
    if (segsz <= CAP2) {
        for (int i = s0 + t; i < s1; i += 256) {
            int w = bucketed[i];
            int lc = w & 255;
            int off = loc[lc] + atomicAdd(&cnt[lc], 1);
            stage[off] = w >> 8;
        }
        __syncthreads();
        for (int i = t; i < segsz; i += 256) csr_src[s0 + i] = stage[i];
    } else {
        for (int i = s0 + t; i < s1; i += 256) {
            int w = bucketed[i];
            int lc = w & 255;
            int off = loc[lc] + atomicAdd(&cnt[lc], 1);
            csr_src[s0 + off] = w >> 8;
        }
    }
}

// K8: packed[v] = one 128B line per node: 8 chunks of {h[4j..4j+3] fp16
// (pre-scaled by sqrt(log2e)), hws[4j..4j+3] fp16} with hws = dis*(h@Wgcn).
// The h pre-scale makes passB's fp16 dot land directly in the exp2 domain.
__global__ __launch_bounds__(256) void embed2_kernel(
    const float* __restrict__ h, const void* __restrict__ Wgcn,
    const int* __restrict__ rowptr, const int* __restrict__ flagp,
    uint4* __restrict__ packed, int N)
{
    __shared__ float Wg[HN * HN];
    __shared__ float hs[32][HN + 1];
    __shared__ float ws[32][HN + 1];
    const int tid = threadIdx.x;
    const int isbf = flagp[0];
    for (int i = tid; i < HN * HN; i += 256) Wg[i] = ldf(Wgcn, i, isbf);
    const int n0 = blockIdx.x * 32;
    for (int i = tid; i < 32 * HN; i += 256) {
        int n = i >> 5, f = i & 31;
        hs[n][f] = (n0 + n < N) ? h[(size_t)(n0 + n) * HN + f] : 0.f;
    }
    __syncthreads();
    const int f = tid & 31, ns = tid >> 5;
    #pragma unroll
    for (int g = 0; g < 4; ++g) {
        int n = ns + 8 * g, v = n0 + n;
        float acc = 0.f;
        #pragma unroll
        for (int k = 0; k < HN; ++k) acc += hs[n][k] * Wg[k * HN + f];
        float dis = (v < N) ? rsqrtf((float)(rowptr[v + 1] - rowptr[v]) + 1.0f) : 0.f;
        ws[n][f] = dis * acc;
    }
    __syncthreads();
    const int n = tid >> 3, jj = tid & 7, v = n0 + n;
    if (v < N) {
        uint4 w;
        w.x = pack2h(hs[n][4 * jj + 0] * SQRT_LOG2E, hs[n][4 * jj + 1] * SQRT_LOG2E);
        w.y = pack2h(hs[n][4 * jj + 2] * SQRT_LOG2E, hs[n][4 * jj + 3] * SQRT_LOG2E);
        w.z = pack2h(ws[n][4 * jj + 0], ws[n][4 * jj + 1]);
        w.w = pack2h(ws[n][4 * jj + 2], ws[n][4 * jj + 3]);
        packed[(size_t)v * 8 + jj] = w;
    }
}

// K9 (passB): fused gather pass, online softmax (exp2 domain), fdot2 scores
// on the packed fp16 halves. ONE 128B line per edge, 2x unrolled.
__global__ __launch_bounds__(256) void passB_kernel(
    const float* __restrict__ h, const uint4* __restrict__ packed,
    const int* __restrict__ csr_src, const int* __restrict__ rowptr,
    const void* __restrict__ t, const void* __restrict__ bgcn,
    const int* __restrict__ flagp,
    float* __restrict__ outr, float* __restrict__ outz,
    float* __restrict__ out0_ml, float* __restrict__ denout, int N)
{
    const int tid = threadIdx.x;
    const int lane = tid & 31;
    const int sub = lane >> 3;
    const int j = lane & 7;
    const int v = blockIdx.x * 8 + (tid >> 5);
    if (v >= N) return;
    const int isbf = flagp[0];

    const float4* h4 = (const float4*)h;
    float4 hv = h4[(size_t)v * 8 + j];          // fp32 self (rep path)
    uint4 sw = packed[(size_t)v * 8 + j];       // self line: scaled h + hws
    float2 wsv0 = up2(sw.z), wsv1 = up2(sw.w);
    const int s = rowptr[v], e2 = rowptr[v + 1];

    float m = -1e30f, den = 0.f, num = 0.f;     // m in log2 domain
    float ax = 0.f, ay = 0.f, az = 0.f, aw = 0.f;
    int i = s + sub;
    for (; i + 4 < e2; i += 8) {
        int r0 = csr_src[i];
        int r1 = csr_src[i + 4];
        uint4 w0 = packed[(size_t)r0 * 8 + j];
        uint4 w1 = packed[(size_t)r1 * 8 + j];
        float tr0 = ldf(t, r0, isbf);
        float tr1 = ldf(t, r1, isbf);
        // score in exp2 domain: both operands pre-scaled by sqrt(log2e)
        float p0 = fd2(w0.x, sw.x, fd2(w0.y, sw.y, 0.f));
        float p1 = fd2(w1.x, sw.x, fd2(w1.y, sw.y, 0.f));
        p0 += __shfl_xor(p0, 1, 32);
        p0 += __shfl_xor(p0, 2, 32);
        p0 += __shfl_xor(p0, 4, 32);
        p1 += __shfl_xor(p1, 1, 32);
        p1 += __shfl_xor(p1, 2, 32);
        p1 += __shfl_xor(p1, 4, 32);
        float2 a00 = up2(w0.z), a01 = up2(w0.w);
        float2 a10 = up2(w1.z), a11 = up2(w1.w);
        ax += a00.x + a10.x; ay += a00.y + a10.y;
        az += a01.x + a11.x; aw += a01.y + a11.y;
        float mn = fmaxf(m, fmaxf(p0, p1));
        float corr = exp2f(m - mn);
        float e0 = exp2f(p0 - mn), e1 = exp2f(p1 - mn);
        den = den * corr + e0 + e1;
        num = num * corr + e0 * tr0 + e1 * tr1;
        m = mn;
    }
    if (i < e2) {
        int r0 = csr_src[i];
        uint4 w0 = packed[(size_t)r0 * 8 + j];
        float tr0 = ldf(t, r0, isbf);
        float p0 = fd2(w0.x, sw.x, fd2(w0.y, sw.y, 0.f));
        p0 += __shfl_xor(p0, 1, 32);
        p0 += __shfl_xor(p0, 2, 32);
        p0 += __shfl_xor(p0, 4, 32);
        float2 a00 = up2(w0.z), a01 = up2(w0.w);
        ax += a00.x; ay += a00.y; az += a01.x; aw += a01.y;
        float mn = fmaxf(m, p0);
        float corr = exp2f(m - mn);
        float e0 = exp2f(p0 - mn);
        den = den * corr + e0;
        num = num * corr + e0 * tr0;
        m = mn;
    }
    #pragma unroll
    for (int o = 8; o <= 16; o <<= 1) {
        float mo = __shfl_xor(m, o, 32);
        float dno = __shfl_xor(den, o, 32);
        float nmo = __shfl_xor(num, o, 32);
        float mn = fmaxf(m, mo);
        float ca = exp2f(m - mn), cb = exp2f(mo - mn);
        den = den * ca + dno * cb;
        num = num * ca + nmo * cb;
        m = mn;
        ax += __shfl_xor(ax, o, 32);
        ay += __shfl_xor(ay, o, 32);
        az += __shfl_xor(az, o, 32);
        aw += __shfl_xor(aw, o, 32);
    }

    float dv = rsqrtf((float)(e2 - s) + 1.0f);
    float4 rep;
    rep.x = hv.x + fmaxf(dv * (ax + wsv0.x) + ldf(bgcn, 4 * j + 0, isbf), 0.f);
    rep.y = hv.y + fmaxf(dv * (ay + wsv0.y) + ldf(bgcn, 4 * j + 1, isbf), 0.f);
    rep.z = hv.z + fmaxf(dv * (az + wsv1.x) + ldf(bgcn, 4 * j + 2, isbf), 0.f);
    rep.w = hv.w + fmaxf(dv * (aw + wsv1.y) + ldf(bgcn, 4 * j + 3, isbf), 0.f);
    if (sub == 0)
        ((float4*)outr)[(size_t)v * 8 + j] = rep;
    if (lane == 0) {
        outz[v]    = num / fmaxf(den, 1e-37f);
        out0_ml[v] = m;          // log2 domain
        denout[v]  = den;
    }
}

// K10a/K10b: global max over per-node local maxes
__global__ __launch_bounds__(256) void amax1_kernel(
    const float* __restrict__ ml, float* __restrict__ bmax2, int N)
{
    float m = -INFINITY;
    for (int i = blockIdx.x * 256 + threadIdx.x; i < N; i += 256 * 256)
        m = fmaxf(m, ml[i]);
    #pragma unroll
    for (int s = 32; s; s >>= 1) m = fmaxf(m, __shfl_xor(m, s, 64));
    __shared__ float sm[4];
    if ((threadIdx.x & 63) == 0) sm[threadIdx.x >> 6] = m;
    __syncthreads();
    if (threadIdx.x == 0)
        bmax2[blockIdx.x] = fmaxf(fmaxf(sm[0], sm[1]), fmaxf(sm[2], sm[3]));
}
__global__ __launch_bounds__(256) void amax2_kernel(
    const float* __restrict__ bmax2, float* __restrict__ amax)
{
    float m = bmax2[threadIdx.x];
    #pragma unroll
    for (int s = 32; s; s >>= 1) m = fmaxf(m, __shfl_xor(m, s, 64));
    __shared__ float sm[4];
    if ((threadIdx.x & 63) == 0) sm[threadIdx.x >> 6] = m;
    __syncthreads();
    if (threadIdx.x == 0) amax[0] = fmaxf(fmaxf(sm[0], sm[1]), fmaxf(sm[2], sm[3]));
}

// K11: exact epsilon correction (log2 domain) + FF head.
__global__ __launch_bounds__(256) void final_kernel(
    const float* __restrict__ rep_in,
    const void* __restrict__ t, const int* __restrict__ flagp,
    const float* __restrict__ amax, const float* __restrict__ denarr,
    const void* __restrict__ W1, const void* __restrict__ b1,
    const void* __restrict__ W2, const void* __restrict__ b2,
    float* __restrict__ out0, float* __restrict__ outz, int N)
{
    __shared__ float W1s[34 * HN];
    __shared__ float b1s[HN], W2s[HN];
    __shared__ float b2s;
    const int tid = threadIdx.x;
    const int isbf = flagp[0];
    for (int i = tid; i < 34 * HN; i += 256) W1s[i] = ldf(W1, i, isbf);
    if (tid < HN) {
        b1s[tid] = ldf(b1, tid, isbf);
        W2s[tid] = ldf(W2, tid, isbf);
    }
    if (tid == 0) b2s = ldf(b2, 0, isbf);
    __syncthreads();

    const int lane = tid & 31;
    const int v = blockIdx.x * 8 + (tid >> 5);
    if (v >= N) return;

    float rep = rep_in[(size_t)v * HN + lane];
    float ml  = out0[v];
    float den = denarr[v];
    float zh  = outz[v];
    float am  = amax[0];
    float term = (1e-8f / den) * exp2f(am - ml);   // log2-domain stabilizer
    float z = zh / (1.0f + term);
    float tv = ldf(t, v, isbf);

    float acc = b1s[lane] + tv * W1s[32 * HN + lane] + z * W1s[33 * HN + lane];
    #pragma unroll
    for (int k = 0; k < HN; ++k)
        acc += __shfl(rep, k, 32) * W1s[k * HN + lane];
    float f1 = fmaxf(acc, 0.f);
    float o = f1 * W2s[lane];
    #pragma unroll
    for (int m = 16; m; m >>= 1) o += __shfl_xor(o, m, 32);

    if (lane == 0) {
        out0[v] = o + b2s;
        outz[v] = z;
    }
}

extern "C" void kernel_launch(void* const* d_in, const int* in_sizes, int n_in,
                              void* d_out, int out_size, void* d_ws, size_t ws_size,
                              hipStream_t stream)
{
    const int N = out_size / 34;   // out[N] + rep[N*32] + z[N]
    const int E = in_sizes[2];

    const void* x    = d_in[0];
    const void* t    = d_in[1];
    const int* row   = (const int*)d_in[2];
    const int* col   = (const int*)d_in[3];
    const void* Wemb = d_in[4];
    const void* bemb = d_in[5];
    const void* Wgcn = d_in[6];
    const void* bgcn = d_in[7];
    const void* W1   = d_in[8];
    const void* b1   = d_in[9];
    const void* W2   = d_in[10];
    const void* b2   = d_in[11];

    const int B   = (N + 255) >> 8;         // coarse buckets (<=512 for N<=131072)
    const int NB1 = (E + CH1 - 1) / CH1;    // phase1/bhist blocks

    // ws: h | hwbuf(bucketed->packed) | csr_src | rowptr | den
    //     | bucket_cnt | bucket_base | bucket_cursor | bmax2 | amax | flag
    char* wsb = (char*)d_ws;
    size_t off = 0;
    float* h        = (float*)(wsb + off); off += (size_t)N * HN * 4;
    size_t hwbytes  = (size_t)N * HN * 4;  // == N*128B packed line region
    if ((size_t)E * 4 > hwbytes) hwbytes = (size_t)E * 4;
    char*  hwreg    = wsb + off;           off += hwbytes;
    int*   csr_src  = (int*)(wsb + off);   off += (size_t)E * 4;
    int*   rowptr   = (int*)(wsb + off);   off += (size_t)(N + 1) * 4;
    float* den      = (float*)(wsb + off); off += (size_t)N * 4;
    int*   bucket_cnt    = (int*)(wsb + off); off += (size_t)B * 4;
    int*   bucket_base   = (int*)(wsb + off); off += (size_t)(B + 1) * 4;
    int*   bucket_cursor = (int*)(wsb + off); off += (size_t)B * 4;
    float* bmax2    = (float*)(wsb + off); off += 256 * 4;
    float* amax     = (float*)(wsb + off); off += 4;
    int*   flag     = (int*)(wsb + off);   off += 4;

    int*   bucketed = (int*)hwreg;         // phase 1..2
    uint4* packed   = (uint4*)hwreg;       // after phase2: N x 128B fp16 lines

    hipMemsetAsync(bucket_cnt, 0, (size_t)B * 4, stream);

    bhist_kernel<<<NB1, 512, 0, stream>>>(col, bucket_cnt, E, B,
                                          (const unsigned int*)x, flag);
    embed1_kernel<<<(N + 31) / 32, 256, 0, stream>>>(x, Wemb, bemb, flag, h, N);
    bscan_kernel<<<1, 512, 0, stream>>>(bucket_cnt, bucket_base,
                                        bucket_cursor, rowptr, B, N, E);
    phase1_kernel<<<NB1, 512, 0, stream>>>(row, col, bucket_cursor,
                                           bucketed, E, B);
    phase2_kernel<<<B, 256, 0, stream>>>(bucketed, bucket_base, rowptr,
                                         csr_src, N);
    embed2_kernel<<<(N + 31) / 32, 256, 0, stream>>>(h, Wgcn, rowptr, flag,
                                                     packed, N);

    float* outp = (float*)d_out;
    float* out0 = outp;
    float* outr = outp + N;
    float* outz = outp + (size_t)N * 33;

    passB_kernel<<<(N + 7) / 8, 256, 0, stream>>>(
        h, packed, csr_src, rowptr, t, bgcn, flag, outr, outz, out0, den, N);
    amax1_kernel<<<256, 256, 0, stream>>>(out0, bmax2, N);
    amax2_kernel<<<1, 256, 0, stream>>>(bmax2, amax);
    final_kernel<<<(N + 7) / 8, 256, 0, stream>>>(
        outr, t, flag, amax, den, W1, b1, W2, b2, out0, outz, N);
}

// Round 7
// 335.400 us; speedup vs baseline: 1.3973x; 1.0064x over previous
//
#include <hip/hip_runtime.h>
#include <hip/hip_bf16.h>
#include <hip/hip_fp16.h>

static constexpr int HN = 32;     // Hemb == Hgcn == 32
static constexpr int NIN = 128;
static constexpr int CH1 = 8192;  // edges per phase-1 block
static constexpr int CAP2 = 16384; // LDS stage capacity (ints) in phase 2
// sqrt(log2(e)): folded into packed fp16 h so the score dot is in exp2 domain.
static constexpr float SQRT_LOG2E = 1.2011224087864498f;

typedef _Float16 h2v __attribute__((ext_vector_type(2)));

__device__ __forceinline__ float bf2f(unsigned short u) {
    union { unsigned int i; float f; } v;
    v.i = ((unsigned int)u) << 16;
    return v.f;
}
__device__ __forceinline__ float ldf(const void* p, size_t i, int isbf) {
    return isbf ? bf2f(((const unsigned short*)p)[i]) : ((const float*)p)[i];
}
__device__ __forceinline__ unsigned int pack2h(float a, float b) {
    unsigned short ua = __half_as_ushort(__float2half_rn(a));
    unsigned short ub = __half_as_ushort(__float2half_rn(b));
    return (unsigned int)ua | ((unsigned int)ub << 16);
}
__device__ __forceinline__ float2 up2(unsigned int u) {
    __half2 h2;
    *reinterpret_cast<unsigned int*>(&h2) = u;
    return __half22float2(h2);
}
// packed-fp16 2-way dot-accumulate (v_dot2_f32_f16), f32 accumulator.
__device__ __forceinline__ float fd2(unsigned int a, unsigned int b, float c) {
#if __has_builtin(__builtin_amdgcn_fdot2)
    return __builtin_amdgcn_fdot2(__builtin_bit_cast(h2v, a),
                                  __builtin_bit_cast(h2v, b), c, false);
#else
    float2 fa = up2(a), fb = up2(b);
    return c + fa.x * fb.x + fa.y * fb.y;
#endif
}

// K1: h = relu(x @ Wemb + bemb) -> fp32.
__global__ __launch_bounds__(256) void embed1_kernel(
    const void* __restrict__ x,
    const void* __restrict__ Wemb,
    const void* __restrict__ bemb,
    const int* __restrict__ flagp,
    float* __restrict__ h, int N)
{
    __shared__ float We[NIN * HN];
    __shared__ float be[HN];
    __shared__ float xs[32][NIN];
    const int tid = threadIdx.x;
    const int isbf = flagp[0];

    for (int i = tid; i < NIN * HN; i += 256) We[i] = ldf(Wemb, i, isbf);
    if (tid < HN) be[tid] = ldf(bemb, tid, isbf);

    const int n0 = blockIdx.x * 32;
    if (isbf) {
        const ushort4* x4 = (const ushort4*)((const unsigned short*)x + (size_t)n0 * NIN);
        for (int i = tid; i < 32 * (NIN / 4); i += 256) {
            ushort4 u = x4[i];
            int base = i * 4, n = base >> 7, k = base & (NIN - 1);
            xs[n][k] = bf2f(u.x); xs[n][k + 1] = bf2f(u.y);
            xs[n][k + 2] = bf2f(u.z); xs[n][k + 3] = bf2f(u.w);
        }
    } else {
        const float4* x4 = (const float4*)((const float*)x + (size_t)n0 * NIN);
        for (int i = tid; i < 32 * (NIN / 4); i += 256) {
            float4 u = x4[i];
            int base = i * 4, n = base >> 7, k = base & (NIN - 1);
            xs[n][k] = u.x; xs[n][k + 1] = u.y;
            xs[n][k + 2] = u.z; xs[n][k + 3] = u.w;
        }
    }
    __syncthreads();

    const int f = tid & 31, ns = tid >> 5;
    float a0 = be[f], a1 = be[f], a2 = be[f], a3 = be[f];
    #pragma unroll 8
    for (int k = 0; k < NIN; ++k) {
        float w = We[k * HN + f];
        a0 += xs[ns +  0][k] * w;
        a1 += xs[ns +  8][k] * w;
        a2 += xs[ns + 16][k] * w;
        a3 += xs[ns + 24][k] * w;
    }
    if (n0 + ns      < N) h[(size_t)(n0 + ns     ) * HN + f] = fmaxf(a0, 0.f);
    if (n0 + ns +  8 < N) h[(size_t)(n0 + ns +  8) * HN + f] = fmaxf(a1, 0.f);
    if (n0 + ns + 16 < N) h[(size_t)(n0 + ns + 16) * HN + f] = fmaxf(a2, 0.f);
    if (n0 + ns + 24 < N) h[(size_t)(n0 + ns + 24) * HN + f] = fmaxf(a3, 0.f);
}

// K2: coarse bucket histogram (bucket = col>>8), LDS-aggregated.
// Stores the per-block histogram to blkhist so phase1 can skip recomputing
// it (deletes one 12.8MB col pass + 3.2M LDS atomics from phase1).
// Block 0 lanes 0-63 additionally run the bf16-vs-fp32 input sniff.
__global__ __launch_bounds__(512) void bhist_kernel(
    const int* __restrict__ col, int* __restrict__ bucket_cnt, int E, int B,
    int* __restrict__ blkhist,
    const unsigned int* __restrict__ xw, int* __restrict__ flag)
{
    __shared__ int hist[512];
    const int t = threadIdx.x;
    const int e0 = blockIdx.x * CH1;
    for (int i = t; i < B; i += 512) hist[i] = 0;
    if (blockIdx.x == 0 && t < 64) {
        int hits = 0;
        #pragma unroll
        for (int k = 0; k < 2; ++k) {
            unsigned int w = xw[t + 64 * k];
            float a = bf2f((unsigned short)(w & 0xFFFFu));
            float aa = fabsf(a);
            if (a == 0.0f || (aa >= 0.000244140625f && aa <= 32.0f)) hits++;
        }
        #pragma unroll
        for (int m = 32; m; m >>= 1) hits += __shfl_xor(hits, m, 64);
        if (t == 0) flag[0] = (hits >= 64) ? 1 : 0;
    }
    __syncthreads();
    #pragma unroll
    for (int k = 0; k < CH1 / 512; ++k) {
        int e = e0 + k * 512 + t;
        if (e < E) atomicAdd(&hist[col[e] >> 8], 1);
    }
    __syncthreads();
    for (int i = t; i < B; i += 512) {
        int v = hist[i];
        blkhist[blockIdx.x * B + i] = v;
        if (v) atomicAdd(&bucket_cnt[i], v);
    }
}

// K3: exclusive scan of bucket counts (B <= 512); init cursors; rowptr[N]=E.
__global__ __launch_bounds__(512) void bscan_kernel(
    const int* __restrict__ bucket_cnt, int* __restrict__ bucket_base,
    int* __restrict__ bucket_cursor, int* __restrict__ rowptr,
    int B, int N, int E)
{
    __shared__ int sc[512];
    __shared__ int orig[512];
    const int t = threadIdx.x;
    int v0 = (t < B) ? bucket_cnt[t] : 0;
    sc[t] = v0; orig[t] = v0;
    __syncthreads();
    for (int o = 1; o < 512; o <<= 1) {
        int v = (t >= o) ? sc[t - o] : 0;
        __syncthreads();
        sc[t] += v;
        __syncthreads();
    }
    if (t < B) {
        int ex = sc[t] - orig[t];
        bucket_base[t] = ex;
        bucket_cursor[t] = ex;
    }
    if (t == 0) { bucket_base[B] = E; rowptr[N] = E; }
}

// K4 (phase1): bucketize edges with LDS reorder -> semi-coalesced writes of
// packed words (row<<8 | col&255) grouped by bucket. bucket = col>>8.
// Histogram comes precomputed from bhist via blkhist (single col pass here).
__global__ __launch_bounds__(512) void phase1_kernel(
    const int* __restrict__ row, const int* __restrict__ col,
    const int* __restrict__ blkhist,
    int* __restrict__ bucket_cursor, int* __restrict__ bucketed, int E, int B)
{
    __shared__ int hist[512];
    __shared__ int sc[512];
    __shared__ int cnt[512];
    __shared__ int gbase[512];
    __shared__ int word[CH1];
    __shared__ int dst[CH1];
    const int t = threadIdx.x;
    const int e0 = blockIdx.x * CH1;
    const int M = (E - e0 < CH1) ? (E - e0) : CH1;

    for (int i = t; i < B; i += 512) {
        hist[i] = blkhist[blockIdx.x * B + i];
        cnt[i] = 0;
    }
    __syncthreads();
    sc[t] = (t < B) ? hist[t] : 0;
    __syncthreads();
    for (int o = 1; o < 512; o <<= 1) {
        int v = (t >= o) ? sc[t - o] : 0;
        __syncthreads();
        sc[t] += v;
        __syncthreads();
    }
    if (t < B && hist[t])
        gbase[t] = atomicAdd(&bucket_cursor[t], hist[t]);
    __syncthreads();
    #pragma unroll
    for (int k = 0; k < CH1 / 512; ++k) {
        int e = e0 + k * 512 + t;
        if (e < E) {
            int c = col[e], r = row[e];
            int b = c >> 8;
            int lr = atomicAdd(&cnt[b], 1);
            int p = sc[b] - hist[b] + lr;     // exclusive scan + rank
            word[p] = (r << 8) | (c & 255);
            dst[p] = gbase[b] + lr;
        }
    }
    __syncthreads();
    for (int i = t; i < M; i += 512)
        bucketed[dst[i]] = word[i];
}

// K5 (phase2, fused): one block per bucket. Pass 1 counts per-node degrees
// in LDS; block-scan gives local exclusive offsets -> rowptr written directly.
// Pass 2 places edges via LDS cursors (staged+coalesced when fits CAP2).
__global__ __launch_bounds__(256) void phase2_kernel(
    const int* __restrict__ bucketed, const int* __restrict__ bucket_base,
    int* __restrict__ rowptr, int* __restrict__ csr_src, int N)
{
    __shared__ int stage[CAP2];
    __shared__ int cnt[256];
    __shared__ int sc[256];
    __shared__ int loc[256];
    const int t = threadIdx.x, b = blockIdx.x;
    const int node0 = b << 8;
    const int s0 = bucket_base[b], s1 = bucket_base[b + 1];
    const int segsz = s1 - s0;
    cnt[t] = 0;
    __syncthreads();
    for (int i = s0 + t; i < s1; i += 256)
        atomicAdd(&cnt[bucketed[i] & 255], 1);
    __syncthreads();
    int c = cnt[t];
    sc[t] = c;
    __syncthreads();
    for (int o = 1; o < 256; o <<= 1) {
        int v = (t >= o) ? sc[t - o] : 0;
        __syncthreads();
        sc[t] += v;
        __syncthreads();
    }
    int ex = sc[t] - c;                 // local exclusive offset
    loc[t] = ex;
    if (node0 + t < N) rowptr[node0 + t] = s0 + ex;
    cnt[t] = 0;                         // reuse as placement cursor
    __syncthreads();
    if (segsz <= CAP2) {
        for (int i = s0 + t; i < s1; i += 256) {
            int w = bucketed[i];
            int lc = w & 255;
            int off = loc[lc] + atomicAdd(&cnt[lc], 1);
            stage[off] = w >> 8;
        }
        __syncthreads();
        for (int i = t; i < segsz; i += 256) csr_src[s0 + i] = stage[i];
    } else {
        for (int i = s0 + t; i < s1; i += 256) {
            int w = bucketed[i];
            int lc = w & 255;
            int off = loc[lc] + atomicAdd(&cnt[lc], 1);
            csr_src[s0 + off] = w >> 8;
        }
    }
}

// K8: packed[v] = one 128B line per node: 8 chunks of {h[4j..4j+3] fp16
// (pre-scaled by sqrt(log2e)), hws[4j..4j+3] fp16} with hws = dis*(h@Wgcn).
__global__ __launch_bounds__(256) void embed2_kernel(
    const float* __restrict__ h, const void* __restrict__ Wgcn,
    const int* __restrict__ rowptr, const int* __restrict__ flagp,
    uint4* __restrict__ packed, int N)
{
    __shared__ float Wg[HN * HN];
    __shared__ float hs[32][HN + 1];
    __shared__ float ws[32][HN + 1];
    const int tid = threadIdx.x;
    const int isbf = flagp[0];
    for (int i = tid; i < HN * HN; i += 256) Wg[i] = ldf(Wgcn, i, isbf);
    const int n0 = blockIdx.x * 32;
    for (int i = tid; i < 32 * HN; i += 256) {
        int n = i >> 5, f = i & 31;
        hs[n][f] = (n0 + n < N) ? h[(size_t)(n0 + n) * HN + f] : 0.f;
    }
    __syncthreads();
    const int f = tid & 31, ns = tid >> 5;
    #pragma unroll
    for (int g = 0; g < 4; ++g) {
        int n = ns + 8 * g, v = n0 + n;
        float acc = 0.f;
        #pragma unroll
        for (int k = 0; k < HN; ++k) acc += hs[n][k] * Wg[k * HN + f];
        float dis = (v < N) ? rsqrtf((float)(rowptr[v + 1] - rowptr[v]) + 1.0f) : 0.f;
        ws[n][f] = dis * acc;
    }
    __syncthreads();
    const int n = tid >> 3, jj = tid & 7, v = n0 + n;
    if (v < N) {
        uint4 w;
        w.x = pack2h(hs[n][4 * jj + 0] * SQRT_LOG2E, hs[n][4 * jj + 1] * SQRT_LOG2E);
        w.y = pack2h(hs[n][4 * jj + 2] * SQRT_LOG2E, hs[n][4 * jj + 3] * SQRT_LOG2E);
        w.z = pack2h(ws[n][4 * jj + 0], ws[n][4 * jj + 1]);
        w.w = pack2h(ws[n][4 * jj + 2], ws[n][4 * jj + 3]);
        packed[(size_t)v * 8 + jj] = w;
    }
}

// K9 (passB): fused gather pass, online softmax (exp2 domain), fdot2 scores.
// 4-deep edge unroll: 4 independent packed-line gathers in flight per lane
// to feed the memory pipe (passB is latency-bound at 2.4x its fetch floor).
__global__ __launch_bounds__(256) void passB_kernel(
    const float* __restrict__ h, const uint4* __restrict__ packed,
    const int* __restrict__ csr_src, const int* __restrict__ rowptr,
    const void* __restrict__ t, const void* __restrict__ bgcn,
    const int* __restrict__ flagp,
    float* __restrict__ outr, float* __restrict__ outz,
    float* __restrict__ out0_ml, float* __restrict__ denout, int N)
{
    const int tid = threadIdx.x;
    const int lane = tid & 31;
    const int sub = lane >> 3;
    const int j = lane & 7;
    const int v = blockIdx.x * 8 + (tid >> 5);
    if (v >= N) return;
    const int isbf = flagp[0];

    const float4* h4 = (const float4*)h;
    float4 hv = h4[(size_t)v * 8 + j];          // fp32 self (rep path)
    uint4 sw = packed[(size_t)v * 8 + j];       // self line: scaled h + hws
    float2 wsv0 = up2(sw.z), wsv1 = up2(sw.w);
    const int s = rowptr[v], e2 = rowptr[v + 1];

    float m = -1e30f, den = 0.f, num = 0.f;     // m in log2 domain
    float ax = 0.f, ay = 0.f, az = 0.f, aw = 0.f;
    int i = s + sub;
    for (; i + 12 < e2; i += 16) {
        int r0 = csr_src[i];
        int r1 = csr_src[i + 4];
        int r2 = csr_src[i + 8];
        int r3 = csr_src[i + 12];
        uint4 w0 = packed[(size_t)r0 * 8 + j];
        uint4 w1 = packed[(size_t)r1 * 8 + j];
        uint4 w2 = packed[(size_t)r2 * 8 + j];
        uint4 w3 = packed[(size_t)r3 * 8 + j];
        float tr0 = ldf(t, r0, isbf);
        float tr1 = ldf(t, r1, isbf);
        float tr2 = ldf(t, r2, isbf);
        float tr3 = ldf(t, r3, isbf);
        float p0 = fd2(w0.x, sw.x, fd2(w0.y, sw.y, 0.f));
        float p1 = fd2(w1.x, sw.x, fd2(w1.y, sw.y, 0.f));
        float p2 = fd2(w2.x, sw.x, fd2(w2.y, sw.y, 0.f));
        float p3 = fd2(w3.x, sw.x, fd2(w3.y, sw.y, 0.f));
        p0 += __shfl_xor(p0, 1, 32);
        p0 += __shfl_xor(p0, 2, 32);
        p0 += __shfl_xor(p0, 4, 32);
        p1 += __shfl_xor(p1, 1, 32);
        p1 += __shfl_xor(p1, 2, 32);
        p1 += __shfl_xor(p1, 4, 32);
        p2 += __shfl_xor(p2, 1, 32);
        p2 += __shfl_xor(p2, 2, 32);
        p2 += __shfl_xor(p2, 4, 32);
        p3 += __shfl_xor(p3, 1, 32);
        p3 += __shfl_xor(p3, 2, 32);
        p3 += __shfl_xor(p3, 4, 32);
        float2 a00 = up2(w0.z), a01 = up2(w0.w);
        float2 a10 = up2(w1.z), a11 = up2(w1.w);
        float2 a20 = up2(w2.z), a21 = up2(w2.w);
        float2 a30 = up2(w3.z), a31 = up2(w3.w);
        ax += (a00.x + a10.x) + (a20.x + a30.x);
        ay += (a00.y + a10.y) + (a20.y + a30.y);
        az += (a01.x + a11.x) + (a21.x + a31.x);
        aw += (a01.y + a11.y) + (a21.y + a31.y);
        float mn = fmaxf(m, fmaxf(fmaxf(p0, p1), fmaxf(p2, p3)));
        float corr = exp2f(m - mn);
        float e0 = exp2f(p0 - mn), e1 = exp2f(p1 - mn);
        float e2x = exp2f(p2 - mn), e3 = exp2f(p3 - mn);
        den = den * corr + (e0 + e1) + (e2x + e3);
        num = num * corr + (e0 * tr0 + e1 * tr1) + (e2x * tr2 + e3 * tr3);
        m = mn;
    }
    for (; i + 4 < e2; i += 8) {
        int r0 = csr_src[i];
        int r1 = csr_src[i + 4];
        uint4 w0 = packed[(size_t)r0 * 8 + j];
        uint4 w1 = packed[(size_t)r1 * 8 + j];
        float tr0 = ldf(t, r0, isbf);
        float tr1 = ldf(t, r1, isbf);
        float p0 = fd2(w0.x, sw.x, fd2(w0.y, sw.y, 0.f));
        float p1 = fd2(w1.x, sw.x, fd2(w1.y, sw.y, 0.f));
        p0 += __shfl_xor(p0, 1, 32);
        p0 += __shfl_xor(p0, 2, 32);
        p0 += __shfl_xor(p0, 4, 32);
        p1 += __shfl_xor(p1, 1, 32);
        p1 += __shfl_xor(p1, 2, 32);
        p1 += __shfl_xor(p1, 4, 32);
        float2 a00 = up2(w0.z), a01 = up2(w0.w);
        float2 a10 = up2(w1.z), a11 = up2(w1.w);
        ax += a00.x + a10.x; ay += a00.y + a10.y;
        az += a01.x + a11.x; aw += a01.y + a11.y;
        float mn = fmaxf(m, fmaxf(p0, p1));
        float corr = exp2f(m - mn);
        float e0 = exp2f(p0 - mn), e1 = exp2f(p1 - mn);
        den = den * corr + e0 + e1;
        num = num * corr + e0 * tr0 + e1 * tr1;
        m = mn;
    }
    if (i < e2) {
        int r0 = csr_src[i];
        uint4 w0 = packed[(size_t)r0 * 8 + j];
        float tr0 = ldf(t, r0, isbf);
        float p0 = fd2(w0.x, sw.x, fd2(w0.y, sw.y, 0.f));
        p0 += __shfl_xor(p0, 1, 32);
        p0 += __shfl_xor(p0, 2, 32);
        p0 += __shfl_xor(p0, 4, 32);
        float2 a00 = up2(w0.z), a01 = up2(w0.w);
        ax += a00.x; ay += a00.y; az += a01.x; aw += a01.y;
        float mn = fmaxf(m, p0);
        float corr = exp2f(m - mn);
        float e0 = exp2f(p0 - mn);
        den = den * corr + e0;
        num = num * corr + e0 * tr0;
        m = mn;
    }
    #pragma unroll
    for (int o = 8; o <= 16; o <<= 1) {
        float mo = __shfl_xor(m, o, 32);
        float dno = __shfl_xor(den, o, 32);
        float nmo = __shfl_xor(num, o, 32);
        float mn = fmaxf(m, mo);
        float ca = exp2f(m - mn), cb = exp2f(mo - mn);
        den = den * ca + dno * cb;
        num = num * ca + nmo * cb;
        m = mn;
        ax += __shfl_xor(ax, o, 32);
        ay += __shfl_xor(ay, o, 32);
        az += __shfl_xor(az, o, 32);
        aw += __shfl_xor(aw, o, 32);
    }

    float dv = rsqrtf((float)(e2 - s) + 1.0f);
    float4 rep;
    rep.x = hv.x + fmaxf(dv * (ax + wsv0.x) + ldf(bgcn, 4 * j + 0, isbf), 0.f);
    rep.y = hv.y + fmaxf(dv * (ay + wsv0.y) + ldf(bgcn, 4 * j + 1, isbf), 0.f);
    rep.z = hv.z + fmaxf(dv * (az + wsv1.x) + ldf(bgcn, 4 * j + 2, isbf), 0.f);
    rep.w = hv.w + fmaxf(dv * (aw + wsv1.y) + ldf(bgcn, 4 * j + 3, isbf), 0.f);
    if (sub == 0)
        ((float4*)outr)[(size_t)v * 8 + j] = rep;
    if (lane == 0) {
        outz[v]    = num / fmaxf(den, 1e-37f);
        out0_ml[v] = m;          // log2 domain
        denout[v]  = den;
    }
}

// K10a/K10b: global max over per-node local maxes
__global__ __launch_bounds__(256) void amax1_kernel(
    const float* __restrict__ ml, float* __restrict__ bmax2, int N)
{
    float m = -INFINITY;
    for (int i = blockIdx.x * 256 + threadIdx.x; i < N; i += 256 * 256)
        m = fmaxf(m, ml[i]);
    #pragma unroll
    for (int s = 32; s; s >>= 1) m = fmaxf(m, __shfl_xor(m, s, 64));
    __shared__ float sm[4];
    if ((threadIdx.x & 63) == 0) sm[threadIdx.x >> 6] = m;
    __syncthreads();
    if (threadIdx.x == 0)
        bmax2[blockIdx.x] = fmaxf(fmaxf(sm[0], sm[1]), fmaxf(sm[2], sm[3]));
}
__global__ __launch_bounds__(256) void amax2_kernel(
    const float* __restrict__ bmax2, float* __restrict__ amax)
{
    float m = bmax2[threadIdx.x];
    #pragma unroll
    for (int s = 32; s; s >>= 1) m = fmaxf(m, __shfl_xor(m, s, 64));
    __shared__ float sm[4];
    if ((threadIdx.x & 63) == 0) sm[threadIdx.x >> 6] = m;
    __syncthreads();
    if (threadIdx.x == 0) amax[0] = fmaxf(fmaxf(sm[0], sm[1]), fmaxf(sm[2], sm[3]));
}

// K11: exact epsilon correction (log2 domain) + FF head.
__global__ __launch_bounds__(256) void final_kernel(
    const float* __restrict__ rep_in,
    const void* __restrict__ t, const int* __restrict__ flagp,
    const float* __restrict__ amax, const float* __restrict__ denarr,
    const void* __restrict__ W1, const void* __restrict__ b1,
    const void* __restrict__ W2, const void* __restrict__ b2,
    float* __restrict__ out0, float* __restrict__ outz, int N)
{
    __shared__ float W1s[34 * HN];
    __shared__ float b1s[HN], W2s[HN];
    __shared__ float b2s;
    const int tid = threadIdx.x;
    const int isbf = flagp[0];
    for (int i = tid; i < 34 * HN; i += 256) W1s[i] = ldf(W1, i, isbf);
    if (tid < HN) {
        b1s[tid] = ldf(b1, tid, isbf);
        W2s[tid] = ldf(W2, tid, isbf);
    }
    if (tid == 0) b2s = ldf(b2, 0, isbf);
    __syncthreads();

    const int lane = tid & 31;
    const int v = blockIdx.x * 8 + (tid >> 5);
    if (v >= N) return;

    float rep = rep_in[(size_t)v * HN + lane];
    float ml  = out0[v];
    float den = denarr[v];
    float zh  = outz[v];
    float am  = amax[0];
    float term = (1e-8f / den) * exp2f(am - ml);   // log2-domain stabilizer
    float z = zh / (1.0f + term);
    float tv = ldf(t, v, isbf);

    float acc = b1s[lane] + tv * W1s[32 * HN + lane] + z * W1s[33 * HN + lane];
    #pragma unroll
    for (int k = 0; k < HN; ++k)
        acc += __shfl(rep, k, 32) * W1s[k * HN + lane];
    float f1 = fmaxf(acc, 0.f);
    float o = f1 * W2s[lane];
    #pragma unroll
    for (int m = 16; m; m >>= 1) o += __shfl_xor(o, m, 32);

    if (lane == 0) {
        out0[v] = o + b2s;
        outz[v] = z;
    }
}

extern "C" void kernel_launch(void* const* d_in, const int* in_sizes, int n_in,
                              void* d_out, int out_size, void* d_ws, size_t ws_size,
                              hipStream_t stream)
{
    const int N = out_size / 34;   // out[N] + rep[N*32] + z[N]
    const int E = in_sizes[2];

    const void* x    = d_in[0];
    const void* t    = d_in[1];
    const int* row   = (const int*)d_in[2];
    const int* col   = (const int*)d_in[3];
    const void* Wemb = d_in[4];
    const void* bemb = d_in[5];
    const void* Wgcn = d_in[6];
    const void* bgcn = d_in[7];
    const void* W1   = d_in[8];
    const void* b1   = d_in[9];
    const void* W2   = d_in[10];
    const void* b2   = d_in[11];

    const int B   = (N + 255) >> 8;         // coarse buckets (<=512 for N<=131072)
    const int NB1 = (E + CH1 - 1) / CH1;    // phase1/bhist blocks

    // ws: h | hwbuf(bucketed->packed) | csr_src | rowptr | den
    //     | bucket_cnt | bucket_base | bucket_cursor | bmax2 | amax | flag
    char* wsb = (char*)d_ws;
    size_t off = 0;
    float* h        = (float*)(wsb + off); off += (size_t)N * HN * 4;
    size_t hwbytes  = (size_t)N * HN * 4;  // == N*128B packed line region
    if ((size_t)E * 4 > hwbytes) hwbytes = (size_t)E * 4;
    char*  hwreg    = wsb + off;           off += hwbytes;
    int*   csr_src  = (int*)(wsb + off);   off += (size_t)E * 4;
    int*   rowptr   = (int*)(wsb + off);   off += (size_t)(N + 1) * 4;
    float* den      = (float*)(wsb + off); off += (size_t)N * 4;
    int*   bucket_cnt    = (int*)(wsb + off); off += (size_t)B * 4;
    int*   bucket_base   = (int*)(wsb + off); off += (size_t)(B + 1) * 4;
    int*   bucket_cursor = (int*)(wsb + off); off += (size_t)B * 4;
    float* bmax2    = (float*)(wsb + off); off += 256 * 4;
    float* amax     = (float*)(wsb + off); off += 4;
    int*   flag     = (int*)(wsb + off);   off += 4;

    int*   bucketed = (int*)hwreg;         // phase 1..2
    uint4* packed   = (uint4*)hwreg;       // after phase2: N x 128B fp16 lines
    // blkhist parks in the csr_src region (dead until phase2 overwrites it;
    // phase1 consumes blkhist strictly before phase2 runs). NB1*B ints ~306KB.
    int*   blkhist  = csr_src;

    hipMemsetAsync(bucket_cnt, 0, (size_t)B * 4, stream);

    bhist_kernel<<<NB1, 512, 0, stream>>>(col, bucket_cnt, E, B, blkhist,
                                          (const unsigned int*)x, flag);
    embed1_kernel<<<(N + 31) / 32, 256, 0, stream>>>(x, Wemb, bemb, flag, h, N);
    bscan_kernel<<<1, 512, 0, stream>>>(bucket_cnt, bucket_base,
                                        bucket_cursor, rowptr, B, N, E);
    phase1_kernel<<<NB1, 512, 0, stream>>>(row, col, blkhist, bucket_cursor,
                                           bucketed, E, B);
    phase2_kernel<<<B, 256, 0, stream>>>(bucketed, bucket_base, rowptr,
                                         csr_src, N);
    embed2_kernel<<<(N + 31) / 32, 256, 0, stream>>>(h, Wgcn, rowptr, flag,
                                                     packed, N);

    float* outp = (float*)d_out;
    float* out0 = outp;
    float* outr = outp + N;
    float* outz = outp + (size_t)N * 33;

    passB_kernel<<<(N + 7) / 8, 256, 0, stream>>>(
        h, packed, csr_src, rowptr, t, bgcn, flag, outr, outz, out0, den, N);
    amax1_kernel<<<256, 256, 0, stream>>>(out0, bmax2, N);
    amax2_kernel<<<1, 256, 0, stream>>>(bmax2, amax);
    final_kernel<<<(N + 7) / 8, 256, 0, stream>>>(
        outr, t, flag, amax, den, W1, b1, W2, b2, out0, outz, N);
}

// Round 9
// 335.139 us; speedup vs baseline: 1.3984x; 1.0008x over previous
//
#include <hip/hip_runtime.h>
#include <hip/hip_bf16.h>
#include <hip/hip_fp16.h>

static constexpr int HN = 32;     // Hemb == Hgcn == 32
static constexpr int NIN = 128;
static constexpr int CH1 = 8192;  // edges per phase-1 block
static constexpr int CAP2 = 12288; // LDS stage capacity (ints) in phase 2
                                   // (mean segsz ~8192, std ~90 -> +45 sigma)
// sqrt(log2(e)): folded into packed fp16 h so the score dot is in exp2 domain.
static constexpr float SQRT_LOG2E = 1.2011224087864498f;

typedef _Float16 h2v __attribute__((ext_vector_type(2)));

__device__ __forceinline__ float bf2f(unsigned short u) {
    union { unsigned int i; float f; } v;
    v.i = ((unsigned int)u) << 16;
    return v.f;
}
__device__ __forceinline__ float ldf(const void* p, size_t i, int isbf) {
    return isbf ? bf2f(((const unsigned short*)p)[i]) : ((const float*)p)[i];
}
__device__ __forceinline__ unsigned int pack2h(float a, float b) {
    unsigned short ua = __half_as_ushort(__float2half_rn(a));
    unsigned short ub = __half_as_ushort(__float2half_rn(b));
    return (unsigned int)ua | ((unsigned int)ub << 16);
}
__device__ __forceinline__ float2 up2(unsigned int u) {
    __half2 h2;
    *reinterpret_cast<unsigned int*>(&h2) = u;
    return __half22float2(h2);
}
// packed-fp16 2-way dot-accumulate (v_dot2_f32_f16), f32 accumulator.
__device__ __forceinline__ float fd2(unsigned int a, unsigned int b, float c) {
#if __has_builtin(__builtin_amdgcn_fdot2)
    return __builtin_amdgcn_fdot2(__builtin_bit_cast(h2v, a),
                                  __builtin_bit_cast(h2v, b), c, false);
#else
    float2 fa = up2(a), fb = up2(b);
    return c + fa.x * fb.x + fa.y * fb.y;
#endif
}
// order-preserving float->uint map for atomicMax-based global max
__device__ __forceinline__ unsigned int fmap(float f) {
    unsigned int u = __float_as_uint(f);
    return (f >= 0.f) ? (u | 0x80000000u) : ~u;
}
__device__ __forceinline__ float funmap(unsigned int u) {
    return (u & 0x80000000u) ? __uint_as_float(u & 0x7FFFFFFFu)
                             : __uint_as_float(~u);
}

// K1: h = relu(x @ Wemb + bemb) -> fp32.
__global__ __launch_bounds__(256) void embed1_kernel(
    const void* __restrict__ x,
    const void* __restrict__ Wemb,
    const void* __restrict__ bemb,
    const int* __restrict__ flagp,
    float* __restrict__ h, int N)
{
    __shared__ float We[NIN * HN];
    __shared__ float be[HN];
    __shared__ float xs[32][NIN];
    const int tid = threadIdx.x;
    const int isbf = flagp[0];

    for (int i = tid; i < NIN * HN; i += 256) We[i] = ldf(Wemb, i, isbf);
    if (tid < HN) be[tid] = ldf(bemb, tid, isbf);

    const int n0 = blockIdx.x * 32;
    if (isbf) {
        const ushort4* x4 = (const ushort4*)((const unsigned short*)x + (size_t)n0 * NIN);
        for (int i = tid; i < 32 * (NIN / 4); i += 256) {
            ushort4 u = x4[i];
            int base = i * 4, n = base >> 7, k = base & (NIN - 1);
            xs[n][k] = bf2f(u.x); xs[n][k + 1] = bf2f(u.y);
            xs[n][k + 2] = bf2f(u.z); xs[n][k + 3] = bf2f(u.w);
        }
    } else {
        const float4* x4 = (const float4*)((const float*)x + (size_t)n0 * NIN);
        for (int i = tid; i < 32 * (NIN / 4); i += 256) {
            float4 u = x4[i];
            int base = i * 4, n = base >> 7, k = base & (NIN - 1);
            xs[n][k] = u.x; xs[n][k + 1] = u.y;
            xs[n][k + 2] = u.z; xs[n][k + 3] = u.w;
        }
    }
    __syncthreads();

    const int f = tid & 31, ns = tid >> 5;
    float a0 = be[f], a1 = be[f], a2 = be[f], a3 = be[f];
    #pragma unroll 8
    for (int k = 0; k < NIN; ++k) {
        float w = We[k * HN + f];
        a0 += xs[ns +  0][k] * w;
        a1 += xs[ns +  8][k] * w;
        a2 += xs[ns + 16][k] * w;
        a3 += xs[ns + 24][k] * w;
    }
    if (n0 + ns      < N) h[(size_t)(n0 + ns     ) * HN + f] = fmaxf(a0, 0.f);
    if (n0 + ns +  8 < N) h[(size_t)(n0 + ns +  8) * HN + f] = fmaxf(a1, 0.f);
    if (n0 + ns + 16 < N) h[(size_t)(n0 + ns + 16) * HN + f] = fmaxf(a2, 0.f);
    if (n0 + ns + 24 < N) h[(size_t)(n0 + ns + 24) * HN + f] = fmaxf(a3, 0.f);
}

// K2: coarse bucket histogram (bucket = col>>8), LDS-aggregated; stores
// per-block histogram to blkhist for phase1 reuse. Block 0 lanes 0-63 run
// the bf16-vs-fp32 input sniff.
__global__ __launch_bounds__(512) void bhist_kernel(
    const int* __restrict__ col, int* __restrict__ bucket_cnt, int E, int B,
    int* __restrict__ blkhist,
    const unsigned int* __restrict__ xw, int* __restrict__ flag)
{
    __shared__ int hist[512];
    const int t = threadIdx.x;
    const int e0 = blockIdx.x * CH1;
    for (int i = t; i < B; i += 512) hist[i] = 0;
    if (blockIdx.x == 0 && t < 64) {
        int hits = 0;
        #pragma unroll
        for (int k = 0; k < 2; ++k) {
            unsigned int w = xw[t + 64 * k];
            float a = bf2f((unsigned short)(w & 0xFFFFu));
            float aa = fabsf(a);
            if (a == 0.0f || (aa >= 0.000244140625f && aa <= 32.0f)) hits++;
        }
        #pragma unroll
        for (int m = 32; m; m >>= 1) hits += __shfl_xor(hits, m, 64);
        if (t == 0) flag[0] = (hits >= 64) ? 1 : 0;
    }
    __syncthreads();
    #pragma unroll
    for (int k = 0; k < CH1 / 512; ++k) {
        int e = e0 + k * 512 + t;
        if (e < E) atomicAdd(&hist[col[e] >> 8], 1);
    }
    __syncthreads();
    for (int i = t; i < B; i += 512) {
        int v = hist[i];
        blkhist[blockIdx.x * B + i] = v;
        if (v) atomicAdd(&bucket_cnt[i], v);
    }
}

// K3: exclusive scan of bucket counts (B <= 512); init cursors; rowptr[N]=E.
__global__ __launch_bounds__(512) void bscan_kernel(
    const int* __restrict__ bucket_cnt, int* __restrict__ bucket_base,
    int* __restrict__ bucket_cursor, int* __restrict__ rowptr,
    int B, int N, int E)
{
    __shared__ int sc[512];
    __shared__ int orig[512];
    const int t = threadIdx.x;
    int v0 = (t < B) ? bucket_cnt[t] : 0;
    sc[t] = v0; orig[t] = v0;
    __syncthreads();
    for (int o = 1; o < 512; o <<= 1) {
        int v = (t >= o) ? sc[t - o] : 0;
        __syncthreads();
        sc[t] += v;
        __syncthreads();
    }
    if (t < B) {
        int ex = sc[t] - orig[t];
        bucket_base[t] = ex;
        bucket_cursor[t] = ex;
    }
    if (t == 0) { bucket_base[B] = E; rowptr[N] = E; }
}

// K4 (phase1): bucketize edges with LDS reorder -> semi-coalesced writes of
// packed words (row<<8 | col&255) grouped by bucket. bucket = col>>8.
// Histogram comes precomputed from bhist via blkhist (single col pass here).
__global__ __launch_bounds__(512) void phase1_kernel(
    const int* __restrict__ row, const int* __restrict__ col,
    const int* __restrict__ blkhist,
    int* __restrict__ bucket_cursor, int* __restrict__ bucketed, int E, int B)
{
    __shared__ int hist[512];
    __shared__ int sc[512];
    __shared__ int cnt[512];
    __shared__ int gbase[512];
    __shared__ int word[CH1];
    __shared__ int dst[CH1];
    const int t = threadIdx.x;
    const int e0 = blockIdx.x * CH1;
    const int M = (E - e0 < CH1) ? (E - e0) : CH1;

    for (int i = t; i < B; i += 512) {
        hist[i] = blkhist[blockIdx.x * B + i];
        cnt[i] = 0;
    }
    __syncthreads();
    sc[t] = (t < B) ? hist[t] : 0;
    __syncthreads();
    for (int o = 1; o < 512; o <<= 1) {
        int v = (t >= o) ? sc[t - o] : 0;
        __syncthreads();
        sc[t] += v;
        __syncthreads();
    }
    if (t < B && hist[t])
        gbase[t] = atomicAdd(&bucket_cursor[t], hist[t]);
    __syncthreads();
    #pragma unroll
    for (int k = 0; k < CH1 / 512; ++k) {
        int e = e0 + k * 512 + t;
        if (e < E) {
            int c = col[e], r = row[e];
            int b = c >> 8;
            int lr = atomicAdd(&cnt[b], 1);
            int p = sc[b] - hist[b] + lr;     // exclusive scan + rank
            word[p] = (r << 8) | (c & 255);
            dst[p] = gbase[b] + lr;
        }
    }
    __syncthreads();
    for (int i = t; i < M; i += 512)
        bucketed[dst[i]] = word[i];
}

// K5 (phase2): one block per bucket. Pass 1 counts per-node degrees AND
// saves each edge's per-node rank (rank_s, u16) — so pass 2 places edges
// with pure arithmetic, eliminating the former second 3.2M-atomic pass.
// Block-scan -> rowptr written directly; staged coalesced copy-out.
__global__ __launch_bounds__(256) void phase2_kernel(
    const int* __restrict__ bucketed, const int* __restrict__ bucket_base,
    int* __restrict__ rowptr, int* __restrict__ csr_src, int N)
{
    __shared__ int stage[CAP2];
    __shared__ unsigned short rank_s[CAP2];
    __shared__ int cnt[256];
    __shared__ int sc[256];
    __shared__ int loc[256];
    const int t = threadIdx.x, b = blockIdx.x;
    const int node0 = b << 8;
    const int s0 = bucket_base[b], s1 = bucket_base[b + 1];
    const int segsz = s1 - s0;
    cnt[t] = 0;
    __syncthreads();
    for (int i = s0 + t; i < s1; i += 256) {
        int lc = bucketed[i] & 255;
        int r = atomicAdd(&cnt[lc], 1);
        if (i - s0 < CAP2) rank_s[i - s0] = (unsigned short)r;
    }
    __syncthreads();
    int c = cnt[t];
    sc[t] = c;
    __syncthreads();
    for (int o = 1; o < 256; o <<= 1) {
        int v = (t >= o) ? sc[t - o] : 0;
        __syncthreads();
        sc[t] += v;
        __syncthreads();
    }
    int ex = sc[t] - c;                 // local exclusive offset
    loc[t] = ex;
    if (node0 + t < N) rowptr[node0 + t] = s0 + ex;
    cnt[t] = 0;                         // placement cursor (fallback path only)
    __syncthreads();
    if (segsz <= CAP2) {
        for (int i = s0 + t; i < s1; i += 256) {
            int w = bucketed[i];
            stage[loc[w & 255] + rank_s[i - s0]] = w >> 8;
        }
        __syncthreads();
        for (int i = t; i < segsz; i += 256) csr_src[s0 + i] = stage[i];
    } else {
        for (int i = s0 + t; i < s1; i += 256) {
            int w = bucketed[i];
            int lc = w & 255;
            int off = loc[lc] + atomicAdd(&cnt[lc], 1);
            csr_src[s0 + off] = w >> 8;
        }
    }
}

// K8: packed[v] = one 128B line per node: 8 chunks of {h[4j..4j+3] fp16
// (pre-scaled by sqrt(log2e)), hws[4j..4j+3] fp16} with hws = dis*(h@Wgcn).
__global__ __launch_bounds__(256) void embed2_kernel(
    const float* __restrict__ h, const void* __restrict__ Wgcn,
    const int* __restrict__ rowptr, const int* __restrict__ flagp,
    uint4* __restrict__ packed, int N)
{
    __shared__ float Wg[HN * HN];
    __shared__ float hs[32][HN + 1];
    __shared__ float ws[32][HN + 1];
    const int tid = threadIdx.x;
    const int isbf = flagp[0];
    for (int i = tid; i < HN * HN; i += 256) Wg[i] = ldf(Wgcn, i, isbf);
    const int n0 = blockIdx.x * 32;
    for (int i = tid; i < 32 * HN; i += 256) {
        int n = i >> 5, f = i & 31;
        hs[n][f] = (n0 + n < N) ? h[(size_t)(n0 + n) * HN + f] : 0.f;
    }
    __syncthreads();
    const int f = tid & 31, ns = tid >> 5;
    #pragma unroll
    for (int g = 0; g < 4; ++g) {
        int n = ns + 8 * g, v = n0 + n;
        float acc = 0.f;
        #pragma unroll
        for (int k = 0; k < HN; ++k) acc += hs[n][k] * Wg[k * HN + f];
        float dis = (v < N) ? rsqrtf((float)(rowptr[v + 1] - rowptr[v]) + 1.0f) : 0.f;
        ws[n][f] = dis * acc;
    }
    __syncthreads();
    const int n = tid >> 3, jj = tid & 7, v = n0 + n;
    if (v < N) {
        uint4 w;
        w.x = pack2h(hs[n][4 * jj + 0] * SQRT_LOG2E, hs[n][4 * jj + 1] * SQRT_LOG2E);
        w.y = pack2h(hs[n][4 * jj + 2] * SQRT_LOG2E, hs[n][4 * jj + 3] * SQRT_LOG2E);
        w.z = pack2h(ws[n][4 * jj + 0], ws[n][4 * jj + 1]);
        w.w = pack2h(ws[n][4 * jj + 2], ws[n][4 * jj + 3]);
        packed[(size_t)v * 8 + jj] = w;
    }
}

// K9 (passB): fused gather pass, online softmax (exp2 domain), fdot2 scores.
// 4-deep edge unroll. Unchanged from round 7 (at its structure's floor).
__global__ __launch_bounds__(256) void passB_kernel(
    const float* __restrict__ h, const uint4* __restrict__ packed,
    const int* __restrict__ csr_src, const int* __restrict__ rowptr,
    const void* __restrict__ t, const void* __restrict__ bgcn,
    const int* __restrict__ flagp,
    float* __restrict__ outr, float* __restrict__ outz,
    float* __restrict__ out0_ml, float* __restrict__ denout, int N)
{
    const int tid = threadIdx.x;
    const int lane = tid & 31;
    const int sub = lane >> 3;
    const int j = lane & 7;
    const int v = blockIdx.x * 8 + (tid >> 5);
    if (v >= N) return;
    const int isbf = flagp[0];

    const float4* h4 = (const float4*)h;
    float4 hv = h4[(size_t)v * 8 + j];          // fp32 self (rep path)
    uint4 sw = packed[(size_t)v * 8 + j];       // self line: scaled h + hws
    float2 wsv0 = up2(sw.z), wsv1 = up2(sw.w);
    const int s = rowptr[v], e2 = rowptr[v + 1];

    float m = -1e30f, den = 0.f, num = 0.f;     // m in log2 domain
    float ax = 0.f, ay = 0.f, az = 0.f, aw = 0.f;
    int i = s + sub;
    for (; i + 12 < e2; i += 16) {
        int r0 = csr_src[i];
        int r1 = csr_src[i + 4];
        int r2 = csr_src[i + 8];
        int r3 = csr_src[i + 12];
        uint4 w0 = packed[(size_t)r0 * 8 + j];
        uint4 w1 = packed[(size_t)r1 * 8 + j];
        uint4 w2 = packed[(size_t)r2 * 8 + j];
        uint4 w3 = packed[(size_t)r3 * 8 + j];
        float tr0 = ldf(t, r0, isbf);
        float tr1 = ldf(t, r1, isbf);
        float tr2 = ldf(t, r2, isbf);
        float tr3 = ldf(t, r3, isbf);
        float p0 = fd2(w0.x, sw.x, fd2(w0.y, sw.y, 0.f));
        float p1 = fd2(w1.x, sw.x, fd2(w1.y, sw.y, 0.f));
        float p2 = fd2(w2.x, sw.x, fd2(w2.y, sw.y, 0.f));
        float p3 = fd2(w3.x, sw.x, fd2(w3.y, sw.y, 0.f));
        p0 += __shfl_xor(p0, 1, 32);
        p0 += __shfl_xor(p0, 2, 32);
        p0 += __shfl_xor(p0, 4, 32);
        p1 += __shfl_xor(p1, 1, 32);
        p1 += __shfl_xor(p1, 2, 32);
        p1 += __shfl_xor(p1, 4, 32);
        p2 += __shfl_xor(p2, 1, 32);
        p2 += __shfl_xor(p2, 2, 32);
        p2 += __shfl_xor(p2, 4, 32);
        p3 += __shfl_xor(p3, 1, 32);
        p3 += __shfl_xor(p3, 2, 32);
        p3 += __shfl_xor(p3, 4, 32);
        float2 a00 = up2(w0.z), a01 = up2(w0.w);
        float2 a10 = up2(w1.z), a11 = up2(w1.w);
        float2 a20 = up2(w2.z), a21 = up2(w2.w);
        float2 a30 = up2(w3.z), a31 = up2(w3.w);
        ax += (a00.x + a10.x) + (a20.x + a30.x);
        ay += (a00.y + a10.y) + (a20.y + a30.y);
        az += (a01.x + a11.x) + (a21.x + a31.x);
        aw += (a01.y + a11.y) + (a21.y + a31.y);
        float mn = fmaxf(m, fmaxf(fmaxf(p0, p1), fmaxf(p2, p3)));
        float corr = exp2f(m - mn);
        float e0 = exp2f(p0 - mn), e1 = exp2f(p1 - mn);
        float e2x = exp2f(p2 - mn), e3 = exp2f(p3 - mn);
        den = den * corr + (e0 + e1) + (e2x + e3);
        num = num * corr + (e0 * tr0 + e1 * tr1) + (e2x * tr2 + e3 * tr3);
        m = mn;
    }
    for (; i + 4 < e2; i += 8) {
        int r0 = csr_src[i];
        int r1 = csr_src[i + 4];
        uint4 w0 = packed[(size_t)r0 * 8 + j];
        uint4 w1 = packed[(size_t)r1 * 8 + j];
        float tr0 = ldf(t, r0, isbf);
        float tr1 = ldf(t, r1, isbf);
        float p0 = fd2(w0.x, sw.x, fd2(w0.y, sw.y, 0.f));
        float p1 = fd2(w1.x, sw.x, fd2(w1.y, sw.y, 0.f));
        p0 += __shfl_xor(p0, 1, 32);
        p0 += __shfl_xor(p0, 2, 32);
        p0 += __shfl_xor(p0, 4, 32);
        p1 += __shfl_xor(p1, 1, 32);
        p1 += __shfl_xor(p1, 2, 32);
        p1 += __shfl_xor(p1, 4, 32);
        float2 a00 = up2(w0.z), a01 = up2(w0.w);
        float2 a10 = up2(w1.z), a11 = up2(w1.w);
        ax += a00.x + a10.x; ay += a00.y + a10.y;
        az += a01.x + a11.x; aw += a01.y + a11.y;
        float mn = fmaxf(m, fmaxf(p0, p1));
        float corr = exp2f(m - mn);
        float e0 = exp2f(p0 - mn), e1 = exp2f(p1 - mn);
        den = den * corr + e0 + e1;
        num = num * corr + e0 * tr0 + e1 * tr1;
        m = mn;
    }
    if (i < e2) {
        int r0 = csr_src[i];
        uint4 w0 = packed[(size_t)r0 * 8 + j];
        float tr0 = ldf(t, r0, isbf);
        float p0 = fd2(w0.x, sw.x, fd2(w0.y, sw.y, 0.f));
        p0 += __shfl_xor(p0, 1, 32);
        p0 += __shfl_xor(p0, 2, 32);
        p0 += __shfl_xor(p0, 4, 32);
        float2 a00 = up2(w0.z), a01 = up2(w0.w);
        ax += a00.x; ay += a00.y; az += a01.x; aw += a01.y;
        float mn = fmaxf(m, p0);
        float corr = exp2f(m - mn);
        float e0 = exp2f(p0 - mn);
        den = den * corr + e0;
        num = num * corr + e0 * tr0;
        m = mn;
    }
    #pragma unroll
    for (int o = 8; o <= 16; o <<= 1) {
        float mo = __shfl_xor(m, o, 32);
        float dno = __shfl_xor(den, o, 32);
        float nmo = __shfl_xor(num, o, 32);
        float mn = fmaxf(m, mo);
        float ca = exp2f(m - mn), cb = exp2f(mo - mn);
        den = den * ca + dno * cb;
        num = num * ca + nmo * cb;
        m = mn;
        ax += __shfl_xor(ax, o, 32);
        ay += __shfl_xor(ay, o, 32);
        az += __shfl_xor(az, o, 32);
        aw += __shfl_xor(aw, o, 32);
    }

    float dv = rsqrtf((float)(e2 - s) + 1.0f);
    float4 rep;
    rep.x = hv.x + fmaxf(dv * (ax + wsv0.x) + ldf(bgcn, 4 * j + 0, isbf), 0.f);
    rep.y = hv.y + fmaxf(dv * (ay + wsv0.y) + ldf(bgcn, 4 * j + 1, isbf), 0.f);
    rep.z = hv.z + fmaxf(dv * (az + wsv1.x) + ldf(bgcn, 4 * j + 2, isbf), 0.f);
    rep.w = hv.w + fmaxf(dv * (aw + wsv1.y) + ldf(bgcn, 4 * j + 3, isbf), 0.f);
    if (sub == 0)
        ((float4*)outr)[(size_t)v * 8 + j] = rep;
    if (lane == 0) {
        outz[v]    = num / fmaxf(den, 1e-37f);
        out0_ml[v] = m;          // log2 domain
        denout[v]  = den;
    }
}

// K10: global max over per-node local maxes -> single global atomicMax
// (order-preserving uint mapping; amax_u pre-zeroed = -inf). Replaces the
// former two-kernel reduction tree.
__global__ __launch_bounds__(256) void amax1_kernel(
    const float* __restrict__ ml, unsigned int* __restrict__ amax_u, int N)
{
    float m = -INFINITY;
    for (int i = blockIdx.x * 256 + threadIdx.x; i < N; i += 256 * 256)
        m = fmaxf(m, ml[i]);
    #pragma unroll
    for (int s = 32; s; s >>= 1) m = fmaxf(m, __shfl_xor(m, s, 64));
    __shared__ float sm[4];
    if ((threadIdx.x & 63) == 0) sm[threadIdx.x >> 6] = m;
    __syncthreads();
    if (threadIdx.x == 0) {
        float bm = fmaxf(fmaxf(sm[0], sm[1]), fmaxf(sm[2], sm[3]));
        atomicMax(amax_u, fmap(bm));
    }
}

// K11: exact epsilon correction (log2 domain) + FF head.
__global__ __launch_bounds__(256) void final_kernel(
    const float* __restrict__ rep_in,
    const void* __restrict__ t, const int* __restrict__ flagp,
    const unsigned int* __restrict__ amax_u, const float* __restrict__ denarr,
    const void* __restrict__ W1, const void* __restrict__ b1,
    const void* __restrict__ W2, const void* __restrict__ b2,
    float* __restrict__ out0, float* __restrict__ outz, int N)
{
    __shared__ float W1s[34 * HN];
    __shared__ float b1s[HN], W2s[HN];
    __shared__ float b2s;
    const int tid = threadIdx.x;
    const int isbf = flagp[0];
    for (int i = tid; i < 34 * HN; i += 256) W1s[i] = ldf(W1, i, isbf);
    if (tid < HN) {
        b1s[tid] = ldf(b1, tid, isbf);
        W2s[tid] = ldf(W2, tid, isbf);
    }
    if (tid == 0) b2s = ldf(b2, 0, isbf);
    __syncthreads();

    const int lane = tid & 31;
    const int v = blockIdx.x * 8 + (tid >> 5);
    if (v >= N) return;

    float rep = rep_in[(size_t)v * HN + lane];
    float ml  = out0[v];
    float den = denarr[v];
    float zh  = outz[v];
    float am  = funmap(amax_u[0]);
    float term = (1e-8f / den) * exp2f(am - ml);   // log2-domain stabilizer
    float z = zh / (1.0f + term);
    float tv = ldf(t, v, isbf);

    float acc = b1s[lane] + tv * W1s[32 * HN + lane] + z * W1s[33 * HN + lane];
    #pragma unroll
    for (int k = 0; k < HN; ++k)
        acc += __shfl(rep, k, 32) * W1s[k * HN + lane];
    float f1 = fmaxf(acc, 0.f);
    float o = f1 * W2s[lane];
    #pragma unroll
    for (int m = 16; m; m >>= 1) o += __shfl_xor(o, m, 32);

    if (lane == 0) {
        out0[v] = o + b2s;
        outz[v] = z;
    }
}

extern "C" void kernel_launch(void* const* d_in, const int* in_sizes, int n_in,
                              void* d_out, int out_size, void* d_ws, size_t ws_size,
                              hipStream_t stream)
{
    const int N = out_size / 34;   // out[N] + rep[N*32] + z[N]
    const int E = in_sizes[2];

    const void* x    = d_in[0];
    const void* t    = d_in[1];
    const int* row   = (const int*)d_in[2];
    const int* col   = (const int*)d_in[3];
    const void* Wemb = d_in[4];
    const void* bemb = d_in[5];
    const void* Wgcn = d_in[6];
    const void* bgcn = d_in[7];
    const void* W1   = d_in[8];
    const void* b1   = d_in[9];
    const void* W2   = d_in[10];
    const void* b2   = d_in[11];

    const int B   = (N + 255) >> 8;         // coarse buckets (<=512 for N<=131072)
    const int NB1 = (E + CH1 - 1) / CH1;    // phase1/bhist blocks

    // ws: h | hwbuf(bucketed->packed) | csr_src | rowptr | den
    //     | bucket_cnt+amax_u (one memset) | bucket_base | bucket_cursor | flag
    char* wsb = (char*)d_ws;
    size_t off = 0;
    float* h        = (float*)(wsb + off); off += (size_t)N * HN * 4;
    size_t hwbytes  = (size_t)N * HN * 4;  // == N*128B packed line region
    if ((size_t)E * 4 > hwbytes) hwbytes = (size_t)E * 4;
    char*  hwreg    = wsb + off;           off += hwbytes;
    int*   csr_src  = (int*)(wsb + off);   off += (size_t)E * 4;
    int*   rowptr   = (int*)(wsb + off);   off += (size_t)(N + 1) * 4;
    float* den      = (float*)(wsb + off); off += (size_t)N * 4;
    int*   bucket_cnt    = (int*)(wsb + off); off += (size_t)B * 4;
    unsigned int* amax_u = (unsigned int*)(wsb + off); off += 4;
    int*   bucket_base   = (int*)(wsb + off); off += (size_t)(B + 1) * 4;
    int*   bucket_cursor = (int*)(wsb + off); off += (size_t)B * 4;
    int*   flag     = (int*)(wsb + off);   off += 4;

    int*   bucketed = (int*)hwreg;         // phase 1..2
    uint4* packed   = (uint4*)hwreg;       // after phase2: N x 128B fp16 lines
    // blkhist parks in the csr_src region (dead until phase2 overwrites it).
    int*   blkhist  = csr_src;

    // zero bucket_cnt AND amax_u (adjacent) in one memset
    hipMemsetAsync(bucket_cnt, 0, (size_t)(B + 1) * 4, stream);

    bhist_kernel<<<NB1, 512, 0, stream>>>(col, bucket_cnt, E, B, blkhist,
                                          (const unsigned int*)x, flag);
    embed1_kernel<<<(N + 31) / 32, 256, 0, stream>>>(x, Wemb, bemb, flag, h, N);
    bscan_kernel<<<1, 512, 0, stream>>>(bucket_cnt, bucket_base,
                                        bucket_cursor, rowptr, B, N, E);
    phase1_kernel<<<NB1, 512, 0, stream>>>(row, col, blkhist, bucket_cursor,
                                           bucketed, E, B);
    phase2_kernel<<<B, 256, 0, stream>>>(bucketed, bucket_base, rowptr,
                                         csr_src, N);
    embed2_kernel<<<(N + 31) / 32, 256, 0, stream>>>(h, Wgcn, rowptr, flag,
                                                     packed, N);

    float* outp = (float*)d_out;
    float* out0 = outp;
    float* outr = outp + N;
    float* outz = outp + (size_t)N * 33;

    passB_kernel<<<(N + 7) / 8, 256, 0, stream>>>(
        h, packed, csr_src, rowptr, t, bgcn, flag, outr, outz, out0, den, N);
    amax1_kernel<<<256, 256, 0, stream>>>(out0, amax_u, N);
    final_kernel<<<(N + 7) / 8, 256, 0, stream>>>(
        outr, t, flag, amax_u, den, W1, b1, W2, b2, out0, outz, N);
}